// Round 5
// baseline (449.396 us; speedup 1.0000x reference)
//
#include <hip/hip_runtime.h>
#include <hip/hip_fp16.h>

// ---------------------------------------------------------------------------
// Complex 2-layer MAP graph conv. Round 4:
//  - single uint2 CSR record {col|nrel<<28, fp16x2 w}: one scattered store
//    per edge in the build, one s_load stream in the gather
//  - dynamic work queue (atomic group grab) in layer kernels: no tail
//    generation, no degree imbalance
//  - streaming 16-deep double-buffered gather, fp16 MFMA GEMV (unchanged)
// ---------------------------------------------------------------------------

typedef __attribute__((ext_vector_type(8))) _Float16 half8;
typedef __attribute__((ext_vector_type(4))) float f32x4;

#define LW 72    // LDS act row stride (halves): 144B rows -> 16B-aligned b128
#define LW3 136  // LDS proj row stride (halves): 272B rows

__device__ __forceinline__ unsigned short hbits(float f) {
  return __half_as_ushort(__float2half_rn(f));
}
__device__ __forceinline__ unsigned packh2(float a, float b) {
  return ((unsigned)hbits(b) << 16) | (unsigned)hbits(a);
}
__device__ __forceinline__ float2 unpackh2(unsigned u) {
  __half2 h = *reinterpret_cast<__half2*>(&u);
  return __half22float2(h);
}

// ---- CSR build ------------------------------------------------------------
__global__ void hist_k(const int* __restrict__ row, int* __restrict__ cnt, int E) {
  int e = blockIdx.x * blockDim.x + threadIdx.x;
  if (e < E) atomicAdd(&cnt[row[e]], 1);
}

__global__ void offs_k(const int* __restrict__ cnt, int* __restrict__ offs,
                       int* __restrict__ cursor, int* __restrict__ total, int N) {
  int n = blockIdx.x * blockDim.x + threadIdx.x;
  int lane = threadIdx.x & 63;
  int v = (n < N) ? cnt[n] : 0;
  int x = v;
#pragma unroll
  for (int d = 1; d < 64; d <<= 1) {
    int t = __shfl_up(x, d);
    if (lane >= d) x += t;
  }
  int excl = x - v;
  int wtot = __shfl(x, 63);
  int base = 0;
  if (lane == 63) base = atomicAdd(total, wtot);
  base = __shfl(base, 63);
  if (n < N) {
    offs[n] = base + excl;
    cursor[n] = base + excl;
  }
}

// record: {col | (row&15)<<28, packh2(wr, wi)} -- ONE scattered 8B store
__global__ void scatter_k(const int* __restrict__ row, const int* __restrict__ col,
                          const float* __restrict__ wsym, const float* __restrict__ qp,
                          const float* __restrict__ ent, const float* __restrict__ cc,
                          int* __restrict__ cursor, uint2* __restrict__ crec, int E) {
  int e = blockIdx.x * blockDim.x + threadIdx.x;
  if (e >= E) return;
  float ph = qp[0] * (ent[e] + cc[e]);
  float s, c;
  sincosf(ph, &s, &c);
  float w = wsym[e];
  int r = row[e];
  int pos = atomicAdd(&cursor[r], 1);
  crec[pos] = make_uint2((unsigned)col[e] | ((unsigned)(r & 15) << 28),
                         packh2(w * c, w * s));
}

// ---- pack input features to fp16x2 u32 ------------------------------------
__global__ void conv_k(const float4* __restrict__ xr, const float4* __restrict__ xi,
                       uint4* __restrict__ xc, int n4) {
  int i = blockIdx.x * 256 + threadIdx.x;
  if (i >= n4) return;
  float4 r = xr[i], m = xi[i];
  xc[i] = make_uint4(packh2(r.x, m.x), packh2(r.y, m.y), packh2(r.z, m.z), packh2(r.w, m.w));
}

// ---- streaming SPMM(16-node group) + MFMA GEMV ----------------------------
// A-frag (16x16x32 f16): lane holds A[lane&15][(lane>>4)*8+j]; A row = node.
// C/D: col(lane&15)=out-feature, row((lane>>4)*4+reg)=node.
struct AccRI {
  f32x4 r[4], i[4];
};

__device__ __forceinline__ AccRI spmm_gemv(
    const unsigned* __restrict__ tbl,
    const int* __restrict__ offs, const int* __restrict__ cnt,
    const uint2* __restrict__ crec,
    const _Float16* __restrict__ sW,
    _Float16* __restrict__ s_ar, _Float16* __restrict__ s_ai,
    int n0, int N, int lane) {
  const int c16 = lane & 15, q16 = lane >> 4;
  int nlast = n0 + 15;
  if (nlast >= N) nlast = N - 1;
  int ebeg = __builtin_amdgcn_readfirstlane(offs[n0]);
  int eend = __builtin_amdgcn_readfirstlane(offs[nlast] + cnt[nlast]);
  int total = eend - ebeg;

  uint2 rA[16], rB[16];
  unsigned vA[16], vB[16];
  float ar = 0.f, ai = 0.f;
  int ni = 0;

#define LOADRECS(base_, recs_)                                        \
  do {                                                                \
    if ((base_) + 16 <= total) {                                      \
      _Pragma("unroll") for (int j = 0; j < 16; ++j)                  \
          (recs_)[j] = crec[ebeg + (base_) + j];                      \
    } else {                                                          \
      _Pragma("unroll") for (int j = 0; j < 16; ++j) {                \
        int idx_ = ((base_) + j < total) ? ebeg + (base_) + j : ebeg; \
        (recs_)[j] = crec[idx_];                                      \
      }                                                               \
    }                                                                 \
  } while (0)

#define ISSUEV(recs_, v_)                                                  \
  do {                                                                     \
    _Pragma("unroll") for (int j = 0; j < 16; ++j)                         \
        (v_)[j] = tbl[(unsigned)((recs_)[j].x & 0x0FFFFFFFu) * 64u + lane]; \
  } while (0)

#define FLUSHTO(nrel_)                      \
  while (ni < (nrel_)) {                    \
    s_ar[ni * LW + lane] = (_Float16)ar;    \
    s_ai[ni * LW + lane] = (_Float16)ai;    \
    ar = 0.f;                               \
    ai = 0.f;                               \
    ++ni;                                   \
  }

#define CONSUME(recs_, v_, base_)                               \
  do {                                                          \
    _Pragma("unroll") for (int j = 0; j < 16; ++j) {            \
      if ((base_) + j >= total) break;                          \
      int nrel_ = (recs_)[j].x >> 28;                           \
      FLUSHTO(nrel_);                                           \
      float2 val_ = unpackh2((v_)[j]);                          \
      float2 wv_ = unpackh2((recs_)[j].y);                      \
      ar = fmaf(wv_.x, val_.x, fmaf(-wv_.y, val_.y, ar));       \
      ai = fmaf(wv_.y, val_.x, fmaf(wv_.x, val_.y, ai));        \
    }                                                           \
  } while (0)

  int nbatch = (total + 15) >> 4;
  if (nbatch > 0) {
    LOADRECS(0, rA);
    ISSUEV(rA, vA);
    if (nbatch > 1) LOADRECS(16, rB);
    for (int b = 0; b < nbatch; b += 2) {
      if (b + 1 < nbatch) ISSUEV(rB, vB);
      CONSUME(rA, vA, b * 16);
      if (b + 2 < nbatch) LOADRECS((b + 2) * 16, rA);
      if (b + 1 < nbatch) {
        if (b + 2 < nbatch) ISSUEV(rA, vA);
        CONSUME(rB, vB, (b + 1) * 16);
        if (b + 3 < nbatch) LOADRECS((b + 3) * 16, rB);
      }
    }
  }
  FLUSHTO(16);
#undef LOADRECS
#undef ISSUEV
#undef FLUSHTO
#undef CONSUME

  half8 a_r[2], a_i[2];
#pragma unroll
  for (int ks = 0; ks < 2; ++ks) {
    int off = c16 * LW + ks * 32 + q16 * 8;
    a_r[ks] = *(const half8*)&s_ar[off];
    a_i[ks] = *(const half8*)&s_ai[off];
  }
  AccRI acc;
#pragma unroll
  for (int nt = 0; nt < 4; ++nt) {
    acc.r[nt] = (f32x4){0.f, 0.f, 0.f, 0.f};
    acc.i[nt] = (f32x4){0.f, 0.f, 0.f, 0.f};
  }
#pragma unroll
  for (int nt = 0; nt < 4; ++nt)
#pragma unroll
    for (int ks = 0; ks < 2; ++ks) {
      half8 b = *(const half8*)&sW[(nt * 16 + c16) * LW + ks * 32 + q16 * 8];
      acc.r[nt] = __builtin_amdgcn_mfma_f32_16x16x32_f16(a_r[ks], b, acc.r[nt], 0, 0, 0);
      acc.i[nt] = __builtin_amdgcn_mfma_f32_16x16x32_f16(a_i[ks], b, acc.i[nt], 0, 0, 0);
    }
  return acc;
}

// ---- layer 1 (dynamic group queue) ----------------------------------------
__global__ void __launch_bounds__(256, 4) layer1_k(
    const unsigned* __restrict__ xc,
    const int* __restrict__ offs, const int* __restrict__ cnt,
    const uint2* __restrict__ crec,
    const float* __restrict__ W, const float* __restrict__ bias,
    unsigned* __restrict__ Hc, int N, int ngroups, int* __restrict__ qctr) {
  __shared__ __align__(16) _Float16 sW[64 * LW];
  __shared__ __align__(16) _Float16 s_act[4][2][16 * LW];
  for (int i = threadIdx.x; i < 64 * 64; i += 256)
    sW[(i >> 6) * LW + (i & 63)] = (_Float16)W[i];
  __syncthreads();
  const int w = threadIdx.x >> 6, lane = threadIdx.x & 63;
  const int c16 = lane & 15, q16 = lane >> 4;
  float bl[4];
#pragma unroll
  for (int nt = 0; nt < 4; ++nt) bl[nt] = 2.f * bias[nt * 16 + c16];

  for (;;) {
    int g = 0;
    if (lane == 0) g = atomicAdd(qctr, 1);
    g = __shfl(g, 0);
    if (g >= ngroups) break;
    int n0 = g * 16;
    AccRI acc = spmm_gemv(xc, offs, cnt, crec, sW,
                          &s_act[w][0][0], &s_act[w][1][0], n0, N, lane);
#pragma unroll
    for (int nt = 0; nt < 4; ++nt)
#pragma unroll
      for (int r = 0; r < 4; ++r) {
        int node = n0 + q16 * 4 + r;
        if (node < N) {
          float hr = fmaxf(acc.r[nt][r], 0.f);
          float hi = fmaxf(acc.i[nt][r] + bl[nt], 0.f);
          Hc[(unsigned)node * 64u + nt * 16 + c16] = packh2(hr, hi);
        }
      }
  }
}

// ---- layer 2 + final [16x128] projection (dynamic group queue) ------------
__global__ void __launch_bounds__(256, 4) layer2_k(
    const unsigned* __restrict__ Hc,
    const int* __restrict__ offs, const int* __restrict__ cnt,
    const uint2* __restrict__ crec,
    const float* __restrict__ W2, const float* __restrict__ b2,
    const float* __restrict__ W3, const float* __restrict__ b3,
    float* __restrict__ out, int N, int ngroups, int* __restrict__ qctr) {
  __shared__ __align__(16) _Float16 sW[64 * LW];
  __shared__ __align__(16) _Float16 sW3p[16 * LW3];
  __shared__ __align__(16) _Float16 s_act[4][2][16 * LW];
  for (int i = threadIdx.x; i < 64 * 64; i += 256)
    sW[(i >> 6) * LW + (i & 63)] = (_Float16)W2[i];
  // interleaved k' = 2f + (0:real,1:imag)  ->  source W3[o][f + 64*ri]
  for (int i = threadIdx.x; i < 16 * 128; i += 256) {
    int o = i >> 7, kp = i & 127;
    sW3p[o * LW3 + kp] = (_Float16)W3[o * 128 + (kp >> 1) + 64 * (kp & 1)];
  }
  __syncthreads();
  const int w = threadIdx.x >> 6, lane = threadIdx.x & 63;
  const int c16 = lane & 15, q16 = lane >> 4;
  float bl[4];
#pragma unroll
  for (int nt = 0; nt < 4; ++nt) bl[nt] = 2.f * b2[nt * 16 + c16];
  const float b3v = b3[c16];

  for (;;) {
    int g = 0;
    if (lane == 0) g = atomicAdd(qctr, 1);
    g = __shfl(g, 0);
    if (g >= ngroups) break;
    int n0 = g * 16;
    AccRI acc = spmm_gemv(Hc, offs, cnt, crec, sW,
                          &s_act[w][0][0], &s_act[w][1][0], n0, N, lane);

    // stage h packed (r,i) per feature into proj buffer (reuses act LDS)
    unsigned* pb = (unsigned*)&s_act[w][0][0];  // [16][68] u32 rows = 136 halves
#pragma unroll
    for (int nt = 0; nt < 4; ++nt)
#pragma unroll
      for (int r = 0; r < 4; ++r) {
        float hr = fmaxf(acc.r[nt][r], 0.f);
        float hi = fmaxf(acc.i[nt][r] + bl[nt], 0.f);
        pb[(q16 * 4 + r) * 68 + nt * 16 + c16] = packh2(hr, hi);
      }
    f32x4 po = {0.f, 0.f, 0.f, 0.f};
#pragma unroll
    for (int ks = 0; ks < 4; ++ks) {
      half8 a = *(const half8*)((const _Float16*)pb + c16 * LW3 + ks * 32 + q16 * 8);
      half8 b = *(const half8*)&sW3p[c16 * LW3 + ks * 32 + q16 * 8];
      po = __builtin_amdgcn_mfma_f32_16x16x32_f16(a, b, po, 0, 0, 0);
    }
#pragma unroll
    for (int r = 0; r < 4; ++r) {
      int node = n0 + q16 * 4 + r;
      if (node < N) out[(unsigned)node * 16u + c16] = po[r] + b3v;
    }
  }
}

extern "C" void kernel_launch(void* const* d_in, const int* in_sizes, int n_in,
                              void* d_out, int out_size, void* d_ws, size_t ws_size,
                              hipStream_t stream) {
  const float* xr   = (const float*)d_in[0];
  const float* xi   = (const float*)d_in[1];
  const float* wsym = (const float*)d_in[2];
  const float* qp   = (const float*)d_in[3];
  const float* ent  = (const float*)d_in[4];
  const float* cc   = (const float*)d_in[5];
  const float* W1   = (const float*)d_in[6];
  const float* b1   = (const float*)d_in[7];
  const float* W2   = (const float*)d_in[8];
  const float* b2   = (const float*)d_in[9];
  const float* W3   = (const float*)d_in[10];
  const float* b3   = (const float*)d_in[11];
  const int*   row  = (const int*)d_in[12];
  const int*   col  = (const int*)d_in[13];
  const int N = in_sizes[0] / 64;
  const int E = in_sizes[2];
  float* out = (float*)d_out;

  char* ws = (char*)d_ws;
  size_t off = 0;
  auto alloc = [&](size_t bytes) -> void* {
    void* p = ws + off;
    off += (bytes + 255) & ~(size_t)255;
    return p;
  };
  int*      cnt    = (int*)alloc((size_t)N * 4);
  int*      offs   = (int*)alloc((size_t)N * 4);
  int*      cursor = (int*)alloc((size_t)N * 4);
  int*      total  = (int*)alloc(256);  // [0]=scan base, [1]=q1, [2]=q2
  uint2*    crec   = (uint2*)alloc((size_t)E * 8);
  unsigned* xc     = (unsigned*)alloc((size_t)N * 64 * 4);
  unsigned* Hc     = (unsigned*)alloc((size_t)N * 64 * 4);

  hipMemsetAsync(cnt, 0, (size_t)N * 4, stream);
  hipMemsetAsync(total, 0, 256, stream);
  int n4 = N * 64 / 4;
  conv_k<<<(n4 + 255) / 256, 256, 0, stream>>>((const float4*)xr, (const float4*)xi,
                                               (uint4*)xc, n4);
  hist_k<<<(E + 255) / 256, 256, 0, stream>>>(row, cnt, E);
  offs_k<<<(N + 255) / 256, 256, 0, stream>>>(cnt, offs, cursor, total, N);
  scatter_k<<<(E + 255) / 256, 256, 0, stream>>>(row, col, wsym, qp, ent, cc,
                                                 cursor, crec, E);
  int ngroups = (N + 15) / 16;
  int nb = 1280;  // ~residency capacity (5 blocks/CU x 256 CU); queue balances
  layer1_k<<<nb, 256, 0, stream>>>(xc, offs, cnt, crec, W1, b1, Hc, N,
                                   ngroups, &total[1]);
  layer2_k<<<nb, 256, 0, stream>>>(Hc, offs, cnt, crec, W2, b2, W3, b3, out, N,
                                   ngroups, &total[2]);
}

// Round 6
// 302.918 us; speedup vs baseline: 1.4836x; 1.4836x over previous
//
#include <hip/hip_runtime.h>
#include <hip/hip_fp16.h>

// ---------------------------------------------------------------------------
// Complex 2-layer MAP graph conv. Round 5:
//  - REVERT dynamic queue (round-5 regression: atomic on critical path +
//    divergent-looking control flow): static one-group-per-wave mapping.
//  - Weight B-fragments hoisted to registers (8 half8/lane for W, 4 for W3):
//    no weight LDS, no __syncthreads at all; LDS 32K->18.4K for occupancy.
//  - uint2 CSR record kept (single scattered 8B store in build).
//  - 16-deep double-buffered streaming gather, fp16 MFMA (unchanged).
// ---------------------------------------------------------------------------

typedef __attribute__((ext_vector_type(8))) _Float16 half8;
typedef __attribute__((ext_vector_type(4))) float f32x4;

#define LW 72  // LDS act row stride (halves): 144B rows -> 16B-aligned b128

__device__ __forceinline__ unsigned short hbits(float f) {
  return __half_as_ushort(__float2half_rn(f));
}
__device__ __forceinline__ unsigned packh2(float a, float b) {
  return ((unsigned)hbits(b) << 16) | (unsigned)hbits(a);
}
__device__ __forceinline__ float2 unpackh2(unsigned u) {
  __half2 h = *reinterpret_cast<__half2*>(&u);
  return __half22float2(h);
}
// 8 consecutive floats -> half8
__device__ __forceinline__ half8 cvt8(const float* __restrict__ p) {
  float4 lo = *(const float4*)p;
  float4 hi = *(const float4*)(p + 4);
  half8 h;
  h[0] = (_Float16)lo.x; h[1] = (_Float16)lo.y;
  h[2] = (_Float16)lo.z; h[3] = (_Float16)lo.w;
  h[4] = (_Float16)hi.x; h[5] = (_Float16)hi.y;
  h[6] = (_Float16)hi.z; h[7] = (_Float16)hi.w;
  return h;
}
// interleave 4 real + 4 imag floats -> half8 (k' = 2f + ri)
__device__ __forceinline__ half8 cvt8_ri(const float* __restrict__ pr,
                                         const float* __restrict__ pi) {
  float4 r = *(const float4*)pr;
  float4 m = *(const float4*)pi;
  half8 h;
  h[0] = (_Float16)r.x; h[1] = (_Float16)m.x;
  h[2] = (_Float16)r.y; h[3] = (_Float16)m.y;
  h[4] = (_Float16)r.z; h[5] = (_Float16)m.z;
  h[6] = (_Float16)r.w; h[7] = (_Float16)m.w;
  return h;
}

// ---- CSR build ------------------------------------------------------------
__global__ void hist_k(const int* __restrict__ row, int* __restrict__ cnt, int E) {
  int e = blockIdx.x * blockDim.x + threadIdx.x;
  if (e < E) atomicAdd(&cnt[row[e]], 1);
}

__global__ void offs_k(const int* __restrict__ cnt, int* __restrict__ offs,
                       int* __restrict__ cursor, int* __restrict__ total, int N) {
  int n = blockIdx.x * blockDim.x + threadIdx.x;
  int lane = threadIdx.x & 63;
  int v = (n < N) ? cnt[n] : 0;
  int x = v;
#pragma unroll
  for (int d = 1; d < 64; d <<= 1) {
    int t = __shfl_up(x, d);
    if (lane >= d) x += t;
  }
  int excl = x - v;
  int wtot = __shfl(x, 63);
  int base = 0;
  if (lane == 63) base = atomicAdd(total, wtot);
  base = __shfl(base, 63);
  if (n < N) {
    offs[n] = base + excl;
    cursor[n] = base + excl;
  }
}

// record: {col | (row&15)<<28, packh2(wr, wi)} -- ONE scattered 8B store
__global__ void scatter_k(const int* __restrict__ row, const int* __restrict__ col,
                          const float* __restrict__ wsym, const float* __restrict__ qp,
                          const float* __restrict__ ent, const float* __restrict__ cc,
                          int* __restrict__ cursor, uint2* __restrict__ crec, int E) {
  int e = blockIdx.x * blockDim.x + threadIdx.x;
  if (e >= E) return;
  float ph = qp[0] * (ent[e] + cc[e]);
  float s, c;
  sincosf(ph, &s, &c);
  float w = wsym[e];
  int r = row[e];
  int pos = atomicAdd(&cursor[r], 1);
  crec[pos] = make_uint2((unsigned)col[e] | ((unsigned)(r & 15) << 28),
                         packh2(w * c, w * s));
}

// ---- pack input features to fp16x2 u32 ------------------------------------
__global__ void conv_k(const float4* __restrict__ xr, const float4* __restrict__ xi,
                       uint4* __restrict__ xc, int n4) {
  int i = blockIdx.x * 256 + threadIdx.x;
  if (i >= n4) return;
  float4 r = xr[i], m = xi[i];
  xc[i] = make_uint4(packh2(r.x, m.x), packh2(r.y, m.y), packh2(r.z, m.z), packh2(r.w, m.w));
}

// ---- streaming SPMM(16-node group) + MFMA GEMV ----------------------------
// A-frag (16x16x32 f16): lane holds A[lane&15][(lane>>4)*8+j]; A row = node.
// B-frag (registers):    lane holds B[k][n] = W[n=lane&15][k] slices.
// C/D: col(lane&15)=out-feature, row((lane>>4)*4+reg)=node.
struct AccRI {
  f32x4 r[4], i[4];
};

__device__ __forceinline__ AccRI spmm_gemv(
    const unsigned* __restrict__ tbl,
    const int* __restrict__ offs, const int* __restrict__ cnt,
    const uint2* __restrict__ crec,
    const half8 (&bw)[4][2],
    _Float16* __restrict__ s_ar, _Float16* __restrict__ s_ai,
    int n0, int N, int lane) {
  const int c16 = lane & 15, q16 = lane >> 4;
  int nlast = n0 + 15;
  if (nlast >= N) nlast = N - 1;
  int ebeg = __builtin_amdgcn_readfirstlane(offs[n0]);
  int eend = __builtin_amdgcn_readfirstlane(offs[nlast] + cnt[nlast]);
  int total = eend - ebeg;

  uint2 rA[16], rB[16];
  unsigned vA[16], vB[16];
  float ar = 0.f, ai = 0.f;
  int ni = 0;

#define LOADRECS(base_, recs_)                                        \
  do {                                                                \
    if ((base_) + 16 <= total) {                                      \
      _Pragma("unroll") for (int j = 0; j < 16; ++j)                  \
          (recs_)[j] = crec[ebeg + (base_) + j];                      \
    } else {                                                          \
      _Pragma("unroll") for (int j = 0; j < 16; ++j) {                \
        int idx_ = ((base_) + j < total) ? ebeg + (base_) + j : ebeg; \
        (recs_)[j] = crec[idx_];                                      \
      }                                                               \
    }                                                                 \
  } while (0)

#define ISSUEV(recs_, v_)                                                  \
  do {                                                                     \
    _Pragma("unroll") for (int j = 0; j < 16; ++j)                         \
        (v_)[j] = tbl[(unsigned)((recs_)[j].x & 0x0FFFFFFFu) * 64u + lane]; \
  } while (0)

#define FLUSHTO(nrel_)                      \
  while (ni < (nrel_)) {                    \
    s_ar[ni * LW + lane] = (_Float16)ar;    \
    s_ai[ni * LW + lane] = (_Float16)ai;    \
    ar = 0.f;                               \
    ai = 0.f;                               \
    ++ni;                                   \
  }

#define CONSUME(recs_, v_, base_)                               \
  do {                                                          \
    _Pragma("unroll") for (int j = 0; j < 16; ++j) {            \
      if ((base_) + j >= total) break;                          \
      int nrel_ = (recs_)[j].x >> 28;                           \
      FLUSHTO(nrel_);                                           \
      float2 val_ = unpackh2((v_)[j]);                          \
      float2 wv_ = unpackh2((recs_)[j].y);                      \
      ar = fmaf(wv_.x, val_.x, fmaf(-wv_.y, val_.y, ar));       \
      ai = fmaf(wv_.y, val_.x, fmaf(wv_.x, val_.y, ai));        \
    }                                                           \
  } while (0)

  int nbatch = (total + 15) >> 4;
  if (nbatch > 0) {
    LOADRECS(0, rA);
    ISSUEV(rA, vA);
    if (nbatch > 1) LOADRECS(16, rB);
    for (int b = 0; b < nbatch; b += 2) {
      if (b + 1 < nbatch) ISSUEV(rB, vB);
      CONSUME(rA, vA, b * 16);
      if (b + 2 < nbatch) LOADRECS((b + 2) * 16, rA);
      if (b + 1 < nbatch) {
        if (b + 2 < nbatch) ISSUEV(rA, vA);
        CONSUME(rB, vB, (b + 1) * 16);
        if (b + 3 < nbatch) LOADRECS((b + 3) * 16, rB);
      }
    }
  }
  FLUSHTO(16);
#undef LOADRECS
#undef ISSUEV
#undef FLUSHTO
#undef CONSUME

  half8 a_r[2], a_i[2];
#pragma unroll
  for (int ks = 0; ks < 2; ++ks) {
    int off = c16 * LW + ks * 32 + q16 * 8;
    a_r[ks] = *(const half8*)&s_ar[off];
    a_i[ks] = *(const half8*)&s_ai[off];
  }
  AccRI acc;
#pragma unroll
  for (int nt = 0; nt < 4; ++nt) {
    acc.r[nt] = (f32x4){0.f, 0.f, 0.f, 0.f};
    acc.i[nt] = (f32x4){0.f, 0.f, 0.f, 0.f};
  }
#pragma unroll
  for (int nt = 0; nt < 4; ++nt)
#pragma unroll
    for (int ks = 0; ks < 2; ++ks) {
      acc.r[nt] = __builtin_amdgcn_mfma_f32_16x16x32_f16(a_r[ks], bw[nt][ks], acc.r[nt], 0, 0, 0);
      acc.i[nt] = __builtin_amdgcn_mfma_f32_16x16x32_f16(a_i[ks], bw[nt][ks], acc.i[nt], 0, 0, 0);
    }
  return acc;
}

// ---- layer 1 (static group map, no barriers) ------------------------------
__global__ void __launch_bounds__(256, 5) layer1_k(
    const unsigned* __restrict__ xc,
    const int* __restrict__ offs, const int* __restrict__ cnt,
    const uint2* __restrict__ crec,
    const float* __restrict__ W, const float* __restrict__ bias,
    unsigned* __restrict__ Hc, int N) {
  __shared__ __align__(16) _Float16 s_act[4][2][16 * LW];
  const int w = threadIdx.x >> 6, lane = threadIdx.x & 63;
  const int c16 = lane & 15, q16 = lane >> 4;
  int n0 = (blockIdx.x * 4 + w) * 16;
  if (n0 >= N) return;

  half8 bw[4][2];  // B-frag: lane holds W[nt*16+c16][ks*32+q16*8 .. +8)
#pragma unroll
  for (int nt = 0; nt < 4; ++nt)
#pragma unroll
    for (int ks = 0; ks < 2; ++ks)
      bw[nt][ks] = cvt8(&W[(nt * 16 + c16) * 64 + ks * 32 + q16 * 8]);
  float bl[4];
#pragma unroll
  for (int nt = 0; nt < 4; ++nt) bl[nt] = 2.f * bias[nt * 16 + c16];

  AccRI acc = spmm_gemv(xc, offs, cnt, crec, bw,
                        &s_act[w][0][0], &s_act[w][1][0], n0, N, lane);
#pragma unroll
  for (int nt = 0; nt < 4; ++nt)
#pragma unroll
    for (int r = 0; r < 4; ++r) {
      int node = n0 + q16 * 4 + r;
      if (node < N) {
        float hr = fmaxf(acc.r[nt][r], 0.f);
        float hi = fmaxf(acc.i[nt][r] + bl[nt], 0.f);
        Hc[(unsigned)node * 64u + nt * 16 + c16] = packh2(hr, hi);
      }
    }
}

// ---- layer 2 + final [16x128] projection ----------------------------------
__global__ void __launch_bounds__(256, 5) layer2_k(
    const unsigned* __restrict__ Hc,
    const int* __restrict__ offs, const int* __restrict__ cnt,
    const uint2* __restrict__ crec,
    const float* __restrict__ W2, const float* __restrict__ b2,
    const float* __restrict__ W3, const float* __restrict__ b3,
    float* __restrict__ out, int N) {
  __shared__ __align__(16) _Float16 s_act[4][2][16 * LW];
  const int w = threadIdx.x >> 6, lane = threadIdx.x & 63;
  const int c16 = lane & 15, q16 = lane >> 4;
  int n0 = (blockIdx.x * 4 + w) * 16;
  if (n0 >= N) return;

  half8 bw[4][2];
#pragma unroll
  for (int nt = 0; nt < 4; ++nt)
#pragma unroll
    for (int ks = 0; ks < 2; ++ks)
      bw[nt][ks] = cvt8(&W2[(nt * 16 + c16) * 64 + ks * 32 + q16 * 8]);
  // W3 interleaved frag: k' = ks*32+q16*8+j, element j: f=k0/2+j/2, ri=j&1
  half8 w3f[4];
#pragma unroll
  for (int ks = 0; ks < 4; ++ks) {
    int f0 = ks * 16 + q16 * 4;  // k0/2
    w3f[ks] = cvt8_ri(&W3[c16 * 128 + f0], &W3[c16 * 128 + 64 + f0]);
  }
  float bl[4];
#pragma unroll
  for (int nt = 0; nt < 4; ++nt) bl[nt] = 2.f * b2[nt * 16 + c16];
  const float b3v = b3[c16];

  AccRI acc = spmm_gemv(Hc, offs, cnt, crec, bw,
                        &s_act[w][0][0], &s_act[w][1][0], n0, N, lane);

  // stage h packed (r,i) per feature into proj buffer (reuses act LDS)
  unsigned* pb = (unsigned*)&s_act[w][0][0];  // [16][68] u32 rows = 136 halves
#pragma unroll
  for (int nt = 0; nt < 4; ++nt)
#pragma unroll
    for (int r = 0; r < 4; ++r) {
      float hr = fmaxf(acc.r[nt][r], 0.f);
      float hi = fmaxf(acc.i[nt][r] + bl[nt], 0.f);
      pb[(q16 * 4 + r) * 68 + nt * 16 + c16] = packh2(hr, hi);
    }
  f32x4 po = {0.f, 0.f, 0.f, 0.f};
#pragma unroll
  for (int ks = 0; ks < 4; ++ks) {
    half8 a = *(const half8*)((const _Float16*)pb + c16 * 136 + ks * 32 + q16 * 8);
    po = __builtin_amdgcn_mfma_f32_16x16x32_f16(a, w3f[ks], po, 0, 0, 0);
  }
#pragma unroll
  for (int r = 0; r < 4; ++r) {
    int node = n0 + q16 * 4 + r;
    if (node < N) out[(unsigned)node * 16u + c16] = po[r] + b3v;
  }
}

extern "C" void kernel_launch(void* const* d_in, const int* in_sizes, int n_in,
                              void* d_out, int out_size, void* d_ws, size_t ws_size,
                              hipStream_t stream) {
  const float* xr   = (const float*)d_in[0];
  const float* xi   = (const float*)d_in[1];
  const float* wsym = (const float*)d_in[2];
  const float* qp   = (const float*)d_in[3];
  const float* ent  = (const float*)d_in[4];
  const float* cc   = (const float*)d_in[5];
  const float* W1   = (const float*)d_in[6];
  const float* b1   = (const float*)d_in[7];
  const float* W2   = (const float*)d_in[8];
  const float* b2   = (const float*)d_in[9];
  const float* W3   = (const float*)d_in[10];
  const float* b3   = (const float*)d_in[11];
  const int*   row  = (const int*)d_in[12];
  const int*   col  = (const int*)d_in[13];
  const int N = in_sizes[0] / 64;
  const int E = in_sizes[2];
  float* out = (float*)d_out;

  char* ws = (char*)d_ws;
  size_t off = 0;
  auto alloc = [&](size_t bytes) -> void* {
    void* p = ws + off;
    off += (bytes + 255) & ~(size_t)255;
    return p;
  };
  int*      cnt    = (int*)alloc((size_t)N * 4);
  int*      offs   = (int*)alloc((size_t)N * 4);
  int*      cursor = (int*)alloc((size_t)N * 4);
  int*      total  = (int*)alloc(256);
  uint2*    crec   = (uint2*)alloc((size_t)E * 8);
  unsigned* xc     = (unsigned*)alloc((size_t)N * 64 * 4);
  unsigned* Hc     = (unsigned*)alloc((size_t)N * 64 * 4);

  hipMemsetAsync(cnt, 0, (size_t)N * 4, stream);
  hipMemsetAsync(total, 0, 256, stream);
  int n4 = N * 64 / 4;
  conv_k<<<(n4 + 255) / 256, 256, 0, stream>>>((const float4*)xr, (const float4*)xi,
                                               (uint4*)xc, n4);
  hist_k<<<(E + 255) / 256, 256, 0, stream>>>(row, cnt, E);
  offs_k<<<(N + 255) / 256, 256, 0, stream>>>(cnt, offs, cursor, total, N);
  scatter_k<<<(E + 255) / 256, 256, 0, stream>>>(row, col, wsym, qp, ent, cc,
                                                 cursor, crec, E);
  int nb = (N + 63) / 64;  // 4 waves/block x 16 nodes/wave, static map
  layer1_k<<<nb, 256, 0, stream>>>(xc, offs, cnt, crec, W1, b1, Hc, N);
  layer2_k<<<nb, 256, 0, stream>>>(Hc, offs, cnt, crec, W2, b2, W3, b3, out, N);
}

// Round 7
// 248.409 us; speedup vs baseline: 1.8091x; 1.2194x over previous
//
#include <hip/hip_runtime.h>
#include <hip/hip_fp16.h>

// ---------------------------------------------------------------------------
// Complex 2-layer MAP graph conv. Round 7:
//  - layers: round-3 proven structure (weight LDS, static one-group-per-wave,
//    16-deep double-buffered streaming gather, fp16 MFMA GEMV, one barrier)
//  - CSR: round-4 uint2 record {col|nrel<<28, fp16x2 w} (single 8B scattered
//    store per edge in the build)
//  - conv+hist fused into one prep kernel; launch_bounds(256,5) (LDS 32.0KB
//    -> 5 blocks/CU)
// ---------------------------------------------------------------------------

typedef __attribute__((ext_vector_type(8))) _Float16 half8;
typedef __attribute__((ext_vector_type(4))) float f32x4;

#define LW 72    // LDS act/weight row stride (halves): 144B rows, 16B-aligned
#define LW3 136  // LDS proj row stride (halves): 272B rows

__device__ __forceinline__ unsigned short hbits(float f) {
  return __half_as_ushort(__float2half_rn(f));
}
__device__ __forceinline__ unsigned packh2(float a, float b) {
  return ((unsigned)hbits(b) << 16) | (unsigned)hbits(a);
}
__device__ __forceinline__ float2 unpackh2(unsigned u) {
  __half2 h = *reinterpret_cast<__half2*>(&u);
  return __half22float2(h);
}

// ---- fused feature-pack + row histogram -----------------------------------
__global__ void prep_k(const float4* __restrict__ xr, const float4* __restrict__ xi,
                       uint4* __restrict__ xc, int n4,
                       const int* __restrict__ row, int* __restrict__ cnt, int E) {
  int i = blockIdx.x * 256 + threadIdx.x;
  if (i < E) atomicAdd(&cnt[row[i]], 1);
  if (i < n4) {
    float4 r = xr[i], m = xi[i];
    xc[i] = make_uint4(packh2(r.x, m.x), packh2(r.y, m.y),
                       packh2(r.z, m.z), packh2(r.w, m.w));
  }
}

__global__ void offs_k(const int* __restrict__ cnt, int* __restrict__ offs,
                       int* __restrict__ cursor, int* __restrict__ total, int N) {
  int n = blockIdx.x * blockDim.x + threadIdx.x;
  int lane = threadIdx.x & 63;
  int v = (n < N) ? cnt[n] : 0;
  int x = v;
#pragma unroll
  for (int d = 1; d < 64; d <<= 1) {
    int t = __shfl_up(x, d);
    if (lane >= d) x += t;
  }
  int excl = x - v;
  int wtot = __shfl(x, 63);
  int base = 0;
  if (lane == 63) base = atomicAdd(total, wtot);
  base = __shfl(base, 63);
  if (n < N) {
    offs[n] = base + excl;
    cursor[n] = base + excl;
  }
}

// record: {col | (row&15)<<28, packh2(wr, wi)} -- ONE scattered 8B store
__global__ void scatter_k(const int* __restrict__ row, const int* __restrict__ col,
                          const float* __restrict__ wsym, const float* __restrict__ qp,
                          const float* __restrict__ ent, const float* __restrict__ cc,
                          int* __restrict__ cursor, uint2* __restrict__ crec, int E) {
  int e = blockIdx.x * blockDim.x + threadIdx.x;
  if (e >= E) return;
  float ph = qp[0] * (ent[e] + cc[e]);
  float s, c;
  sincosf(ph, &s, &c);
  float w = wsym[e];
  int r = row[e];
  int pos = atomicAdd(&cursor[r], 1);
  crec[pos] = make_uint2((unsigned)col[e] | ((unsigned)(r & 15) << 28),
                         packh2(w * c, w * s));
}

// ---- streaming SPMM(16-node group) + MFMA GEMV ----------------------------
// A-frag (16x16x32 f16): lane holds A[lane&15][(lane>>4)*8+j]; A row = node.
// C/D: col(lane&15)=out-feature, row((lane>>4)*4+reg)=node.
struct AccRI {
  f32x4 r[4], i[4];
};

__device__ __forceinline__ AccRI spmm_gemv(
    const unsigned* __restrict__ tbl,
    const int* __restrict__ offs, const int* __restrict__ cnt,
    const uint2* __restrict__ crec,
    const _Float16* __restrict__ sW,
    _Float16* __restrict__ s_ar, _Float16* __restrict__ s_ai,
    int n0, int N, int lane) {
  const int c16 = lane & 15, q16 = lane >> 4;
  int nlast = n0 + 15;
  if (nlast >= N) nlast = N - 1;
  int ebeg = __builtin_amdgcn_readfirstlane(offs[n0]);
  int eend = __builtin_amdgcn_readfirstlane(offs[nlast] + cnt[nlast]);
  int total = eend - ebeg;

  uint2 rA[16], rB[16];
  unsigned vA[16], vB[16];
  float ar = 0.f, ai = 0.f;
  int ni = 0;

#define LOADRECS(base_, recs_)                                        \
  do {                                                                \
    if ((base_) + 16 <= total) {                                      \
      _Pragma("unroll") for (int j = 0; j < 16; ++j)                  \
          (recs_)[j] = crec[ebeg + (base_) + j];                      \
    } else {                                                          \
      _Pragma("unroll") for (int j = 0; j < 16; ++j) {                \
        int idx_ = ((base_) + j < total) ? ebeg + (base_) + j : ebeg; \
        (recs_)[j] = crec[idx_];                                      \
      }                                                               \
    }                                                                 \
  } while (0)

#define ISSUEV(recs_, v_)                                                  \
  do {                                                                     \
    _Pragma("unroll") for (int j = 0; j < 16; ++j)                         \
        (v_)[j] = tbl[(unsigned)((recs_)[j].x & 0x0FFFFFFFu) * 64u + lane]; \
  } while (0)

#define FLUSHTO(nrel_)                      \
  while (ni < (nrel_)) {                    \
    s_ar[ni * LW + lane] = (_Float16)ar;    \
    s_ai[ni * LW + lane] = (_Float16)ai;    \
    ar = 0.f;                               \
    ai = 0.f;                               \
    ++ni;                                   \
  }

#define CONSUME(recs_, v_, base_)                               \
  do {                                                          \
    _Pragma("unroll") for (int j = 0; j < 16; ++j) {            \
      if ((base_) + j >= total) break;                          \
      int nrel_ = (recs_)[j].x >> 28;                           \
      FLUSHTO(nrel_);                                           \
      float2 val_ = unpackh2((v_)[j]);                          \
      float2 wv_ = unpackh2((recs_)[j].y);                      \
      ar = fmaf(wv_.x, val_.x, fmaf(-wv_.y, val_.y, ar));       \
      ai = fmaf(wv_.y, val_.x, fmaf(wv_.x, val_.y, ai));        \
    }                                                           \
  } while (0)

  int nbatch = (total + 15) >> 4;
  if (nbatch > 0) {
    LOADRECS(0, rA);
    ISSUEV(rA, vA);
    if (nbatch > 1) LOADRECS(16, rB);
    for (int b = 0; b < nbatch; b += 2) {
      if (b + 1 < nbatch) ISSUEV(rB, vB);
      CONSUME(rA, vA, b * 16);
      if (b + 2 < nbatch) LOADRECS((b + 2) * 16, rA);
      if (b + 1 < nbatch) {
        if (b + 2 < nbatch) ISSUEV(rA, vA);
        CONSUME(rB, vB, (b + 1) * 16);
        if (b + 3 < nbatch) LOADRECS((b + 3) * 16, rB);
      }
    }
  }
  FLUSHTO(16);
#undef LOADRECS
#undef ISSUEV
#undef FLUSHTO
#undef CONSUME

  half8 a_r[2], a_i[2];
#pragma unroll
  for (int ks = 0; ks < 2; ++ks) {
    int off = c16 * LW + ks * 32 + q16 * 8;
    a_r[ks] = *(const half8*)&s_ar[off];
    a_i[ks] = *(const half8*)&s_ai[off];
  }
  AccRI acc;
#pragma unroll
  for (int nt = 0; nt < 4; ++nt) {
    acc.r[nt] = (f32x4){0.f, 0.f, 0.f, 0.f};
    acc.i[nt] = (f32x4){0.f, 0.f, 0.f, 0.f};
  }
#pragma unroll
  for (int nt = 0; nt < 4; ++nt)
#pragma unroll
    for (int ks = 0; ks < 2; ++ks) {
      half8 b = *(const half8*)&sW[(nt * 16 + c16) * LW + ks * 32 + q16 * 8];
      acc.r[nt] = __builtin_amdgcn_mfma_f32_16x16x32_f16(a_r[ks], b, acc.r[nt], 0, 0, 0);
      acc.i[nt] = __builtin_amdgcn_mfma_f32_16x16x32_f16(a_i[ks], b, acc.i[nt], 0, 0, 0);
    }
  return acc;
}

// ---- layer 1 (static group map, weight LDS) -------------------------------
__global__ void __launch_bounds__(256, 5) layer1_k(
    const unsigned* __restrict__ xc,
    const int* __restrict__ offs, const int* __restrict__ cnt,
    const uint2* __restrict__ crec,
    const float* __restrict__ W, const float* __restrict__ bias,
    unsigned* __restrict__ Hc, int N) {
  __shared__ __align__(16) _Float16 sW[64 * LW];
  __shared__ __align__(16) _Float16 s_act[4][2][16 * LW];
  for (int i = threadIdx.x; i < 64 * 64; i += 256)
    sW[(i >> 6) * LW + (i & 63)] = (_Float16)W[i];
  __syncthreads();
  const int w = threadIdx.x >> 6, lane = threadIdx.x & 63;
  const int c16 = lane & 15, q16 = lane >> 4;
  int n0 = (blockIdx.x * 4 + w) * 16;
  if (n0 >= N) return;
  float bl[4];
#pragma unroll
  for (int nt = 0; nt < 4; ++nt) bl[nt] = 2.f * bias[nt * 16 + c16];

  AccRI acc = spmm_gemv(xc, offs, cnt, crec, sW,
                        &s_act[w][0][0], &s_act[w][1][0], n0, N, lane);
#pragma unroll
  for (int nt = 0; nt < 4; ++nt)
#pragma unroll
    for (int r = 0; r < 4; ++r) {
      int node = n0 + q16 * 4 + r;
      if (node < N) {
        float hr = fmaxf(acc.r[nt][r], 0.f);
        float hi = fmaxf(acc.i[nt][r] + bl[nt], 0.f);
        Hc[(unsigned)node * 64u + nt * 16 + c16] = packh2(hr, hi);
      }
    }
}

// ---- layer 2 + final [16x128] projection ----------------------------------
__global__ void __launch_bounds__(256, 5) layer2_k(
    const unsigned* __restrict__ Hc,
    const int* __restrict__ offs, const int* __restrict__ cnt,
    const uint2* __restrict__ crec,
    const float* __restrict__ W2, const float* __restrict__ b2,
    const float* __restrict__ W3, const float* __restrict__ b3,
    float* __restrict__ out, int N) {
  __shared__ __align__(16) _Float16 sW[64 * LW];
  __shared__ __align__(16) _Float16 sW3p[16 * LW3];
  __shared__ __align__(16) _Float16 s_act[4][2][16 * LW];
  for (int i = threadIdx.x; i < 64 * 64; i += 256)
    sW[(i >> 6) * LW + (i & 63)] = (_Float16)W2[i];
  // interleaved k' = 2f + (0:real,1:imag)  ->  source W3[o][f + 64*ri]
  for (int i = threadIdx.x; i < 16 * 128; i += 256) {
    int o = i >> 7, kp = i & 127;
    sW3p[o * LW3 + kp] = (_Float16)W3[o * 128 + (kp >> 1) + 64 * (kp & 1)];
  }
  __syncthreads();
  const int w = threadIdx.x >> 6, lane = threadIdx.x & 63;
  const int c16 = lane & 15, q16 = lane >> 4;
  int n0 = (blockIdx.x * 4 + w) * 16;
  if (n0 >= N) return;
  float bl[4];
#pragma unroll
  for (int nt = 0; nt < 4; ++nt) bl[nt] = 2.f * b2[nt * 16 + c16];
  const float b3v = b3[c16];

  AccRI acc = spmm_gemv(Hc, offs, cnt, crec, sW,
                        &s_act[w][0][0], &s_act[w][1][0], n0, N, lane);

  // stage h packed (r,i) per feature into proj buffer (reuses act LDS)
  unsigned* pb = (unsigned*)&s_act[w][0][0];  // [16][68] u32 rows = 136 halves
#pragma unroll
  for (int nt = 0; nt < 4; ++nt)
#pragma unroll
    for (int r = 0; r < 4; ++r) {
      float hr = fmaxf(acc.r[nt][r], 0.f);
      float hi = fmaxf(acc.i[nt][r] + bl[nt], 0.f);
      pb[(q16 * 4 + r) * 68 + nt * 16 + c16] = packh2(hr, hi);
    }
  f32x4 po = {0.f, 0.f, 0.f, 0.f};
#pragma unroll
  for (int ks = 0; ks < 4; ++ks) {
    half8 a = *(const half8*)((const _Float16*)pb + c16 * LW3 + ks * 32 + q16 * 8);
    half8 b = *(const half8*)&sW3p[c16 * LW3 + ks * 32 + q16 * 8];
    po = __builtin_amdgcn_mfma_f32_16x16x32_f16(a, b, po, 0, 0, 0);
  }
#pragma unroll
  for (int r = 0; r < 4; ++r) {
    int node = n0 + q16 * 4 + r;
    if (node < N) out[(unsigned)node * 16u + c16] = po[r] + b3v;
  }
}

extern "C" void kernel_launch(void* const* d_in, const int* in_sizes, int n_in,
                              void* d_out, int out_size, void* d_ws, size_t ws_size,
                              hipStream_t stream) {
  const float* xr   = (const float*)d_in[0];
  const float* xi   = (const float*)d_in[1];
  const float* wsym = (const float*)d_in[2];
  const float* qp   = (const float*)d_in[3];
  const float* ent  = (const float*)d_in[4];
  const float* cc   = (const float*)d_in[5];
  const float* W1   = (const float*)d_in[6];
  const float* b1   = (const float*)d_in[7];
  const float* W2   = (const float*)d_in[8];
  const float* b2   = (const float*)d_in[9];
  const float* W3   = (const float*)d_in[10];
  const float* b3   = (const float*)d_in[11];
  const int*   row  = (const int*)d_in[12];
  const int*   col  = (const int*)d_in[13];
  const int N = in_sizes[0] / 64;
  const int E = in_sizes[2];
  float* out = (float*)d_out;

  char* ws = (char*)d_ws;
  size_t off = 0;
  auto alloc = [&](size_t bytes) -> void* {
    void* p = ws + off;
    off += (bytes + 255) & ~(size_t)255;
    return p;
  };
  int*      cnt    = (int*)alloc((size_t)N * 4);
  int*      offs   = (int*)alloc((size_t)N * 4);
  int*      cursor = (int*)alloc((size_t)N * 4);
  int*      total  = (int*)alloc(256);
  uint2*    crec   = (uint2*)alloc((size_t)E * 8);
  unsigned* xc     = (unsigned*)alloc((size_t)N * 64 * 4);
  unsigned* Hc     = (unsigned*)alloc((size_t)N * 64 * 4);

  hipMemsetAsync(cnt, 0, (size_t)N * 4, stream);
  hipMemsetAsync(total, 0, 256, stream);
  int n4 = N * 64 / 4;
  int npre = (n4 > E ? n4 : E);
  prep_k<<<(npre + 255) / 256, 256, 0, stream>>>((const float4*)xr, (const float4*)xi,
                                                 (uint4*)xc, n4, row, cnt, E);
  offs_k<<<(N + 255) / 256, 256, 0, stream>>>(cnt, offs, cursor, total, N);
  scatter_k<<<(E + 255) / 256, 256, 0, stream>>>(row, col, wsym, qp, ent, cc,
                                                 cursor, crec, E);
  int nb = (N + 63) / 64;  // 4 waves/block x 16 nodes/wave, static map
  layer1_k<<<nb, 256, 0, stream>>>(xc, offs, cnt, crec, W1, b1, Hc, N);
  layer2_k<<<nb, 256, 0, stream>>>(Hc, offs, cnt, crec, W2, b2, W3, b3, out, N);
}

// Round 8
// 214.743 us; speedup vs baseline: 2.0927x; 1.1568x over previous
//
#include <hip/hip_runtime.h>
#include <hip/hip_fp16.h>

// ---------------------------------------------------------------------------
// Complex 2-layer MAP graph conv. Round 8:
//  - layers: unchanged round-7 structure (weight LDS, static group map,
//    16-deep double-buffered streaming gather, fp16 MFMA GEMV)
//  - CSR build: two-pass binned scatter to kill 64B-line ping-pong:
//      offs_k: 256-node chunk scan -> contiguous chunk regions + gcur bases
//      bin_k:  LDS-bucketed binning, run-flushes to tmp (full-ish lines)
//      fine_k: per-chunk L2-resident reorder into exact CSR positions
//    tmp aliases Hc (disjoint lifetimes).
// ---------------------------------------------------------------------------

typedef __attribute__((ext_vector_type(8))) _Float16 half8;
typedef __attribute__((ext_vector_type(4))) float f32x4;

#define LW 72    // LDS act/weight row stride (halves): 144B rows, 16B-aligned
#define LW3 136  // LDS proj row stride (halves): 272B rows
#define NBKTMAX 400  // max 256-node chunks (N <= 102400)
#define CAP 16       // LDS records per bucket per tile

__device__ __forceinline__ unsigned short hbits(float f) {
  return __half_as_ushort(__float2half_rn(f));
}
__device__ __forceinline__ unsigned packh2(float a, float b) {
  return ((unsigned)hbits(b) << 16) | (unsigned)hbits(a);
}
__device__ __forceinline__ float2 unpackh2(unsigned u) {
  __half2 h = *reinterpret_cast<__half2*>(&u);
  return __half22float2(h);
}

// ---- fused feature-pack + row histogram -----------------------------------
__global__ void prep_k(const float4* __restrict__ xr, const float4* __restrict__ xi,
                       uint4* __restrict__ xc, int n4,
                       const int* __restrict__ row, int* __restrict__ cnt, int E) {
  int i = blockIdx.x * 256 + threadIdx.x;
  if (i < E) atomicAdd(&cnt[row[i]], 1);
  if (i < n4) {
    float4 r = xr[i], m = xi[i];
    xc[i] = make_uint4(packh2(r.x, m.x), packh2(r.y, m.y),
                       packh2(r.z, m.z), packh2(r.w, m.w));
  }
}

// ---- 256-node chunk scan: offs/cursor + chunk base (gcur) -----------------
__global__ void offs_k(const int* __restrict__ cnt, int* __restrict__ offs,
                       int* __restrict__ cursor, int* __restrict__ total,
                       int* __restrict__ gcur, int N, int nch) {
  int ch = blockIdx.x * 4 + (threadIdx.x >> 6);
  if (ch >= nch) return;
  int lane = threadIdx.x & 63;
  int n0 = ch * 256 + lane * 4;
  int v0 = 0, v1 = 0, v2 = 0, v3 = 0;
  if (n0 + 3 < N) {
    int4 v = *(const int4*)&cnt[n0];
    v0 = v.x; v1 = v.y; v2 = v.z; v3 = v.w;
  } else {
    if (n0 + 0 < N) v0 = cnt[n0 + 0];
    if (n0 + 1 < N) v1 = cnt[n0 + 1];
    if (n0 + 2 < N) v2 = cnt[n0 + 2];
    if (n0 + 3 < N) v3 = cnt[n0 + 3];
  }
  int s = v0 + v1 + v2 + v3;
  int x = s;
#pragma unroll
  for (int d = 1; d < 64; d <<= 1) {
    int t = __shfl_up(x, d);
    if (lane >= d) x += t;
  }
  int excl = x - s;
  int wtot = __shfl(x, 63);
  int base = 0;
  if (lane == 63) base = atomicAdd(total, wtot);
  base = __shfl(base, 63);
  if (lane == 0) gcur[ch] = base;
  int e0 = base + excl;
  if (n0 + 0 < N) { offs[n0 + 0] = e0;                cursor[n0 + 0] = e0; }
  if (n0 + 1 < N) { offs[n0 + 1] = e0 + v0;           cursor[n0 + 1] = e0 + v0; }
  if (n0 + 2 < N) { offs[n0 + 2] = e0 + v0 + v1;      cursor[n0 + 2] = e0 + v0 + v1; }
  if (n0 + 3 < N) { offs[n0 + 3] = e0 + v0 + v1 + v2; cursor[n0 + 3] = e0 + v0 + v1 + v2; }
}

// ---- pass 1: bin edges into per-chunk tmp regions (run flushes) -----------
// tmp record: {col | rowLocal<<24, packh2(wr,wi)}
__global__ void __launch_bounds__(256) bin_k(
    const int* __restrict__ row, const int* __restrict__ col,
    const float* __restrict__ wsym, const float* __restrict__ qp,
    const float* __restrict__ ent, const float* __restrict__ cc,
    int* __restrict__ gcur, uint2* __restrict__ tmp,
    int E, int nbkt, int ntiles) {
  __shared__ int lcnt[NBKTMAX];
  __shared__ uint2 lbuf[NBKTMAX * CAP];
  const float q = qp[0];
  for (int t = blockIdx.x; t < ntiles; t += gridDim.x) {
    for (int i = threadIdx.x; i < nbkt; i += 256) lcnt[i] = 0;
    __syncthreads();
    int base = t * 2048;
#pragma unroll
    for (int j = 0; j < 8; ++j) {
      int e = base + j * 256 + threadIdx.x;
      if (e < E) {
        float ph = q * (ent[e] + cc[e]);
        float s, c;
        sincosf(ph, &s, &c);
        float w = wsym[e];
        int r = row[e];
        uint2 rec = make_uint2((unsigned)col[e] | ((unsigned)(r & 255) << 24),
                               packh2(w * c, w * s));
        int b = r >> 8;
        int pos = atomicAdd(&lcnt[b], 1);
        if (pos < CAP) lbuf[b * CAP + pos] = rec;
        else {  // rare overflow: direct store
          int gp = atomicAdd(&gcur[b], 1);
          tmp[gp] = rec;
        }
      }
    }
    __syncthreads();
    for (int b = threadIdx.x; b < nbkt; b += 256) {
      int c = lcnt[b];
      if (c > CAP) c = CAP;
      if (c > 0) {
        int gp = atomicAdd(&gcur[b], c);
        for (int j = 0; j < c; ++j) tmp[gp + j] = lbuf[b * CAP + j];
      }
    }
    __syncthreads();
  }
}

// ---- pass 2: per-chunk L2-resident reorder to exact CSR positions ---------
__global__ void __launch_bounds__(256) fine_k(
    const uint2* __restrict__ tmp, const int* __restrict__ offs,
    const int* __restrict__ cnt, int* __restrict__ cursor,
    uint2* __restrict__ crec, int N) {
  int b = blockIdx.x;
  int first = b << 8;
  int nlast = first + 256;
  if (nlast > N) nlast = N;
  nlast -= 1;
  int beg = offs[first];
  int end = offs[nlast] + cnt[nlast];
  for (int i = beg + threadIdx.x; i < end; i += 256) {
    uint2 r = tmp[i];
    int node = first + (int)(r.x >> 24);
    unsigned c = r.x & 0xFFFFFFu;
    int pos = atomicAdd(&cursor[node], 1);
    crec[pos] = make_uint2(c | ((unsigned)(node & 15) << 28), r.y);
  }
}

// ---- streaming SPMM(16-node group) + MFMA GEMV ----------------------------
// A-frag (16x16x32 f16): lane holds A[lane&15][(lane>>4)*8+j]; A row = node.
// C/D: col(lane&15)=out-feature, row((lane>>4)*4+reg)=node.
struct AccRI {
  f32x4 r[4], i[4];
};

__device__ __forceinline__ AccRI spmm_gemv(
    const unsigned* __restrict__ tbl,
    const int* __restrict__ offs, const int* __restrict__ cnt,
    const uint2* __restrict__ crec,
    const _Float16* __restrict__ sW,
    _Float16* __restrict__ s_ar, _Float16* __restrict__ s_ai,
    int n0, int N, int lane) {
  const int c16 = lane & 15, q16 = lane >> 4;
  int nlast = n0 + 15;
  if (nlast >= N) nlast = N - 1;
  int ebeg = __builtin_amdgcn_readfirstlane(offs[n0]);
  int eend = __builtin_amdgcn_readfirstlane(offs[nlast] + cnt[nlast]);
  int total = eend - ebeg;

  uint2 rA[16], rB[16];
  unsigned vA[16], vB[16];
  float ar = 0.f, ai = 0.f;
  int ni = 0;

#define LOADRECS(base_, recs_)                                        \
  do {                                                                \
    if ((base_) + 16 <= total) {                                      \
      _Pragma("unroll") for (int j = 0; j < 16; ++j)                  \
          (recs_)[j] = crec[ebeg + (base_) + j];                      \
    } else {                                                          \
      _Pragma("unroll") for (int j = 0; j < 16; ++j) {                \
        int idx_ = ((base_) + j < total) ? ebeg + (base_) + j : ebeg; \
        (recs_)[j] = crec[idx_];                                      \
      }                                                               \
    }                                                                 \
  } while (0)

#define ISSUEV(recs_, v_)                                                  \
  do {                                                                     \
    _Pragma("unroll") for (int j = 0; j < 16; ++j)                         \
        (v_)[j] = tbl[(unsigned)((recs_)[j].x & 0x0FFFFFFFu) * 64u + lane]; \
  } while (0)

#define FLUSHTO(nrel_)                      \
  while (ni < (nrel_)) {                    \
    s_ar[ni * LW + lane] = (_Float16)ar;    \
    s_ai[ni * LW + lane] = (_Float16)ai;    \
    ar = 0.f;                               \
    ai = 0.f;                               \
    ++ni;                                   \
  }

#define CONSUME(recs_, v_, base_)                               \
  do {                                                          \
    _Pragma("unroll") for (int j = 0; j < 16; ++j) {            \
      if ((base_) + j >= total) break;                          \
      int nrel_ = (recs_)[j].x >> 28;                           \
      FLUSHTO(nrel_);                                           \
      float2 val_ = unpackh2((v_)[j]);                          \
      float2 wv_ = unpackh2((recs_)[j].y);                      \
      ar = fmaf(wv_.x, val_.x, fmaf(-wv_.y, val_.y, ar));       \
      ai = fmaf(wv_.y, val_.x, fmaf(wv_.x, val_.y, ai));        \
    }                                                           \
  } while (0)

  int nbatch = (total + 15) >> 4;
  if (nbatch > 0) {
    LOADRECS(0, rA);
    ISSUEV(rA, vA);
    if (nbatch > 1) LOADRECS(16, rB);
    for (int b = 0; b < nbatch; b += 2) {
      if (b + 1 < nbatch) ISSUEV(rB, vB);
      CONSUME(rA, vA, b * 16);
      if (b + 2 < nbatch) LOADRECS((b + 2) * 16, rA);
      if (b + 1 < nbatch) {
        if (b + 2 < nbatch) ISSUEV(rA, vA);
        CONSUME(rB, vB, (b + 1) * 16);
        if (b + 3 < nbatch) LOADRECS((b + 3) * 16, rB);
      }
    }
  }
  FLUSHTO(16);
#undef LOADRECS
#undef ISSUEV
#undef FLUSHTO
#undef CONSUME

  half8 a_r[2], a_i[2];
#pragma unroll
  for (int ks = 0; ks < 2; ++ks) {
    int off = c16 * LW + ks * 32 + q16 * 8;
    a_r[ks] = *(const half8*)&s_ar[off];
    a_i[ks] = *(const half8*)&s_ai[off];
  }
  AccRI acc;
#pragma unroll
  for (int nt = 0; nt < 4; ++nt) {
    acc.r[nt] = (f32x4){0.f, 0.f, 0.f, 0.f};
    acc.i[nt] = (f32x4){0.f, 0.f, 0.f, 0.f};
  }
#pragma unroll
  for (int nt = 0; nt < 4; ++nt)
#pragma unroll
    for (int ks = 0; ks < 2; ++ks) {
      half8 b = *(const half8*)&sW[(nt * 16 + c16) * LW + ks * 32 + q16 * 8];
      acc.r[nt] = __builtin_amdgcn_mfma_f32_16x16x32_f16(a_r[ks], b, acc.r[nt], 0, 0, 0);
      acc.i[nt] = __builtin_amdgcn_mfma_f32_16x16x32_f16(a_i[ks], b, acc.i[nt], 0, 0, 0);
    }
  return acc;
}

// ---- layer 1 (static group map, weight LDS) -------------------------------
__global__ void __launch_bounds__(256, 5) layer1_k(
    const unsigned* __restrict__ xc,
    const int* __restrict__ offs, const int* __restrict__ cnt,
    const uint2* __restrict__ crec,
    const float* __restrict__ W, const float* __restrict__ bias,
    unsigned* __restrict__ Hc, int N) {
  __shared__ __align__(16) _Float16 sW[64 * LW];
  __shared__ __align__(16) _Float16 s_act[4][2][16 * LW];
  for (int i = threadIdx.x; i < 64 * 64; i += 256)
    sW[(i >> 6) * LW + (i & 63)] = (_Float16)W[i];
  __syncthreads();
  const int w = threadIdx.x >> 6, lane = threadIdx.x & 63;
  const int c16 = lane & 15, q16 = lane >> 4;
  int n0 = (blockIdx.x * 4 + w) * 16;
  if (n0 >= N) return;
  float bl[4];
#pragma unroll
  for (int nt = 0; nt < 4; ++nt) bl[nt] = 2.f * bias[nt * 16 + c16];

  AccRI acc = spmm_gemv(xc, offs, cnt, crec, sW,
                        &s_act[w][0][0], &s_act[w][1][0], n0, N, lane);
#pragma unroll
  for (int nt = 0; nt < 4; ++nt)
#pragma unroll
    for (int r = 0; r < 4; ++r) {
      int node = n0 + q16 * 4 + r;
      if (node < N) {
        float hr = fmaxf(acc.r[nt][r], 0.f);
        float hi = fmaxf(acc.i[nt][r] + bl[nt], 0.f);
        Hc[(unsigned)node * 64u + nt * 16 + c16] = packh2(hr, hi);
      }
    }
}

// ---- layer 2 + final [16x128] projection ----------------------------------
__global__ void __launch_bounds__(256, 5) layer2_k(
    const unsigned* __restrict__ Hc,
    const int* __restrict__ offs, const int* __restrict__ cnt,
    const uint2* __restrict__ crec,
    const float* __restrict__ W2, const float* __restrict__ b2,
    const float* __restrict__ W3, const float* __restrict__ b3,
    float* __restrict__ out, int N) {
  __shared__ __align__(16) _Float16 sW[64 * LW];
  __shared__ __align__(16) _Float16 sW3p[16 * LW3];
  __shared__ __align__(16) _Float16 s_act[4][2][16 * LW];
  for (int i = threadIdx.x; i < 64 * 64; i += 256)
    sW[(i >> 6) * LW + (i & 63)] = (_Float16)W2[i];
  // interleaved k' = 2f + (0:real,1:imag)  ->  source W3[o][f + 64*ri]
  for (int i = threadIdx.x; i < 16 * 128; i += 256) {
    int o = i >> 7, kp = i & 127;
    sW3p[o * LW3 + kp] = (_Float16)W3[o * 128 + (kp >> 1) + 64 * (kp & 1)];
  }
  __syncthreads();
  const int w = threadIdx.x >> 6, lane = threadIdx.x & 63;
  const int c16 = lane & 15, q16 = lane >> 4;
  int n0 = (blockIdx.x * 4 + w) * 16;
  if (n0 >= N) return;
  float bl[4];
#pragma unroll
  for (int nt = 0; nt < 4; ++nt) bl[nt] = 2.f * b2[nt * 16 + c16];
  const float b3v = b3[c16];

  AccRI acc = spmm_gemv(Hc, offs, cnt, crec, sW,
                        &s_act[w][0][0], &s_act[w][1][0], n0, N, lane);

  // stage h packed (r,i) per feature into proj buffer (reuses act LDS)
  unsigned* pb = (unsigned*)&s_act[w][0][0];  // [16][68] u32 rows = 136 halves
#pragma unroll
  for (int nt = 0; nt < 4; ++nt)
#pragma unroll
    for (int r = 0; r < 4; ++r) {
      float hr = fmaxf(acc.r[nt][r], 0.f);
      float hi = fmaxf(acc.i[nt][r] + bl[nt], 0.f);
      pb[(q16 * 4 + r) * 68 + nt * 16 + c16] = packh2(hr, hi);
    }
  f32x4 po = {0.f, 0.f, 0.f, 0.f};
#pragma unroll
  for (int ks = 0; ks < 4; ++ks) {
    half8 a = *(const half8*)((const _Float16*)pb + c16 * LW3 + ks * 32 + q16 * 8);
    half8 b = *(const half8*)&sW3p[c16 * LW3 + ks * 32 + q16 * 8];
    po = __builtin_amdgcn_mfma_f32_16x16x32_f16(a, b, po, 0, 0, 0);
  }
#pragma unroll
  for (int r = 0; r < 4; ++r) {
    int node = n0 + q16 * 4 + r;
    if (node < N) out[(unsigned)node * 16u + c16] = po[r] + b3v;
  }
}

extern "C" void kernel_launch(void* const* d_in, const int* in_sizes, int n_in,
                              void* d_out, int out_size, void* d_ws, size_t ws_size,
                              hipStream_t stream) {
  const float* xr   = (const float*)d_in[0];
  const float* xi   = (const float*)d_in[1];
  const float* wsym = (const float*)d_in[2];
  const float* qp   = (const float*)d_in[3];
  const float* ent  = (const float*)d_in[4];
  const float* cc   = (const float*)d_in[5];
  const float* W1   = (const float*)d_in[6];
  const float* b1   = (const float*)d_in[7];
  const float* W2   = (const float*)d_in[8];
  const float* b2   = (const float*)d_in[9];
  const float* W3   = (const float*)d_in[10];
  const float* b3   = (const float*)d_in[11];
  const int*   row  = (const int*)d_in[12];
  const int*   col  = (const int*)d_in[13];
  const int N = in_sizes[0] / 64;
  const int E = in_sizes[2];
  float* out = (float*)d_out;

  char* ws = (char*)d_ws;
  size_t off = 0;
  auto alloc = [&](size_t bytes) -> void* {
    void* p = ws + off;
    off += (bytes + 255) & ~(size_t)255;
    return p;
  };
  int*      cnt    = (int*)alloc((size_t)N * 4);
  int*      offs   = (int*)alloc((size_t)N * 4);
  int*      cursor = (int*)alloc((size_t)N * 4);
  int*      total  = (int*)alloc(256);
  int*      gcur   = (int*)alloc((size_t)NBKTMAX * 4);
  uint2*    crec   = (uint2*)alloc((size_t)E * 8);
  unsigned* xc     = (unsigned*)alloc((size_t)N * 64 * 4);
  unsigned* Hc     = (unsigned*)alloc((size_t)N * 64 * 4);
  uint2*    tmp    = (uint2*)Hc;  // alias: tmp dead before layer1 writes Hc

  hipMemsetAsync(cnt, 0, (size_t)N * 4, stream);
  hipMemsetAsync(total, 0, 256, stream);
  int n4 = N * 64 / 4;
  int npre = (n4 > E ? n4 : E);
  prep_k<<<(npre + 255) / 256, 256, 0, stream>>>((const float4*)xr, (const float4*)xi,
                                                 (uint4*)xc, n4, row, cnt, E);
  int nch = (N + 255) / 256;  // == nbkt
  offs_k<<<(nch + 3) / 4, 256, 0, stream>>>(cnt, offs, cursor, total, gcur, N, nch);
  int ntiles = (E + 2047) / 2048;
  bin_k<<<ntiles, 256, 0, stream>>>(row, col, wsym, qp, ent, cc, gcur, tmp,
                                    E, nch, ntiles);
  fine_k<<<nch, 256, 0, stream>>>(tmp, offs, cnt, cursor, crec, N);
  int nb = (N + 63) / 64;  // 4 waves/block x 16 nodes/wave, static map
  layer1_k<<<nb, 256, 0, stream>>>(xc, offs, cnt, crec, W1, b1, Hc, N);
  layer2_k<<<nb, 256, 0, stream>>>(Hc, offs, cnt, crec, W2, b2, W3, b3, out, N);
}

// Round 9
// 214.550 us; speedup vs baseline: 2.0946x; 1.0009x over previous
//
#include <hip/hip_runtime.h>
#include <hip/hip_fp16.h>

// ---------------------------------------------------------------------------
// Complex 2-layer MAP graph conv. Round 9:
//  - layer kernels: 8 waves/block (512 thr) -> 24 waves/CU (was 20) and a
//    single-generation grid (782 blocks ~= 3/CU); weight-LDS amortized 2x.
//  - bin_k: cooperative flat bucket flush (parallel 8B stores, no serial
//    per-thread runs).
//  - otherwise identical round-8 structure (binned CSR build, streaming
//    16-deep double-buffered gather, fp16 MFMA GEMV).
// ---------------------------------------------------------------------------

typedef __attribute__((ext_vector_type(8))) _Float16 half8;
typedef __attribute__((ext_vector_type(4))) float f32x4;

#define LW 72    // LDS act/weight row stride (halves): 144B rows, 16B-aligned
#define LW3 136  // LDS proj row stride (halves): 272B rows
#define NBKTMAX 400  // max 256-node chunks (N <= 102400)
#define CAP 16       // LDS records per bucket per tile

__device__ __forceinline__ unsigned short hbits(float f) {
  return __half_as_ushort(__float2half_rn(f));
}
__device__ __forceinline__ unsigned packh2(float a, float b) {
  return ((unsigned)hbits(b) << 16) | (unsigned)hbits(a);
}
__device__ __forceinline__ float2 unpackh2(unsigned u) {
  __half2 h = *reinterpret_cast<__half2*>(&u);
  return __half22float2(h);
}

// ---- fused feature-pack + row histogram -----------------------------------
__global__ void prep_k(const float4* __restrict__ xr, const float4* __restrict__ xi,
                       uint4* __restrict__ xc, int n4,
                       const int* __restrict__ row, int* __restrict__ cnt, int E) {
  int i = blockIdx.x * 256 + threadIdx.x;
  if (i < E) atomicAdd(&cnt[row[i]], 1);
  if (i < n4) {
    float4 r = xr[i], m = xi[i];
    xc[i] = make_uint4(packh2(r.x, m.x), packh2(r.y, m.y),
                       packh2(r.z, m.z), packh2(r.w, m.w));
  }
}

// ---- 256-node chunk scan: offs/cursor + chunk base (gcur) -----------------
__global__ void offs_k(const int* __restrict__ cnt, int* __restrict__ offs,
                       int* __restrict__ cursor, int* __restrict__ total,
                       int* __restrict__ gcur, int N, int nch) {
  int ch = blockIdx.x * 4 + (threadIdx.x >> 6);
  if (ch >= nch) return;
  int lane = threadIdx.x & 63;
  int n0 = ch * 256 + lane * 4;
  int v0 = 0, v1 = 0, v2 = 0, v3 = 0;
  if (n0 + 3 < N) {
    int4 v = *(const int4*)&cnt[n0];
    v0 = v.x; v1 = v.y; v2 = v.z; v3 = v.w;
  } else {
    if (n0 + 0 < N) v0 = cnt[n0 + 0];
    if (n0 + 1 < N) v1 = cnt[n0 + 1];
    if (n0 + 2 < N) v2 = cnt[n0 + 2];
    if (n0 + 3 < N) v3 = cnt[n0 + 3];
  }
  int s = v0 + v1 + v2 + v3;
  int x = s;
#pragma unroll
  for (int d = 1; d < 64; d <<= 1) {
    int t = __shfl_up(x, d);
    if (lane >= d) x += t;
  }
  int excl = x - s;
  int wtot = __shfl(x, 63);
  int base = 0;
  if (lane == 63) base = atomicAdd(total, wtot);
  base = __shfl(base, 63);
  if (lane == 0) gcur[ch] = base;
  int e0 = base + excl;
  if (n0 + 0 < N) { offs[n0 + 0] = e0;                cursor[n0 + 0] = e0; }
  if (n0 + 1 < N) { offs[n0 + 1] = e0 + v0;           cursor[n0 + 1] = e0 + v0; }
  if (n0 + 2 < N) { offs[n0 + 2] = e0 + v0 + v1;      cursor[n0 + 2] = e0 + v0 + v1; }
  if (n0 + 3 < N) { offs[n0 + 3] = e0 + v0 + v1 + v2; cursor[n0 + 3] = e0 + v0 + v1 + v2; }
}

// ---- pass 1: bin edges into per-chunk tmp regions (run flushes) -----------
// tmp record: {col | rowLocal<<24, packh2(wr,wi)}
__global__ void __launch_bounds__(256) bin_k(
    const int* __restrict__ row, const int* __restrict__ col,
    const float* __restrict__ wsym, const float* __restrict__ qp,
    const float* __restrict__ ent, const float* __restrict__ cc,
    int* __restrict__ gcur, uint2* __restrict__ tmp,
    int E, int nbkt, int ntiles) {
  __shared__ int lcnt[NBKTMAX];
  __shared__ int lgp[NBKTMAX];
  __shared__ uint2 lbuf[NBKTMAX * CAP];
  const float q = qp[0];
  for (int t = blockIdx.x; t < ntiles; t += gridDim.x) {
    for (int i = threadIdx.x; i < nbkt; i += 256) lcnt[i] = 0;
    __syncthreads();
    int base = t * 2048;
#pragma unroll
    for (int j = 0; j < 8; ++j) {
      int e = base + j * 256 + threadIdx.x;
      if (e < E) {
        float ph = q * (ent[e] + cc[e]);
        float s, c;
        sincosf(ph, &s, &c);
        float w = wsym[e];
        int r = row[e];
        uint2 rec = make_uint2((unsigned)col[e] | ((unsigned)(r & 255) << 24),
                               packh2(w * c, w * s));
        int b = r >> 8;
        int pos = atomicAdd(&lcnt[b], 1);
        if (pos < CAP) lbuf[b * CAP + pos] = rec;
        else {  // rare overflow: direct store
          int gp = atomicAdd(&gcur[b], 1);
          tmp[gp] = rec;
        }
      }
    }
    __syncthreads();
    for (int b = threadIdx.x; b < nbkt; b += 256) {
      int c = lcnt[b];
      if (c > CAP) c = CAP;
      lgp[b] = (c > 0) ? atomicAdd(&gcur[b], c) : 0;
    }
    __syncthreads();
    int slots = nbkt * CAP;
    for (int i = threadIdx.x; i < slots; i += 256) {
      int b = i >> 4, j = i & (CAP - 1);
      int c = lcnt[b];
      if (c > CAP) c = CAP;
      if (j < c) tmp[lgp[b] + j] = lbuf[i];
    }
    __syncthreads();
  }
}

// ---- pass 2: per-chunk L2-resident reorder to exact CSR positions ---------
__global__ void __launch_bounds__(256) fine_k(
    const uint2* __restrict__ tmp, const int* __restrict__ offs,
    const int* __restrict__ cnt, int* __restrict__ cursor,
    uint2* __restrict__ crec, int N) {
  int b = blockIdx.x;
  int first = b << 8;
  int nlast = first + 256;
  if (nlast > N) nlast = N;
  nlast -= 1;
  int beg = offs[first];
  int end = offs[nlast] + cnt[nlast];
  for (int i = beg + threadIdx.x; i < end; i += 256) {
    uint2 r = tmp[i];
    int node = first + (int)(r.x >> 24);
    unsigned c = r.x & 0xFFFFFFu;
    int pos = atomicAdd(&cursor[node], 1);
    crec[pos] = make_uint2(c | ((unsigned)(node & 15) << 28), r.y);
  }
}

// ---- streaming SPMM(16-node group) + MFMA GEMV ----------------------------
// A-frag (16x16x32 f16): lane holds A[lane&15][(lane>>4)*8+j]; A row = node.
// C/D: col(lane&15)=out-feature, row((lane>>4)*4+reg)=node.
struct AccRI {
  f32x4 r[4], i[4];
};

__device__ __forceinline__ AccRI spmm_gemv(
    const unsigned* __restrict__ tbl,
    const int* __restrict__ offs, const int* __restrict__ cnt,
    const uint2* __restrict__ crec,
    const _Float16* __restrict__ sW,
    _Float16* __restrict__ s_ar, _Float16* __restrict__ s_ai,
    int n0, int N, int lane) {
  const int c16 = lane & 15, q16 = lane >> 4;
  int nlast = n0 + 15;
  if (nlast >= N) nlast = N - 1;
  int ebeg = __builtin_amdgcn_readfirstlane(offs[n0]);
  int eend = __builtin_amdgcn_readfirstlane(offs[nlast] + cnt[nlast]);
  int total = eend - ebeg;

  uint2 rA[16], rB[16];
  unsigned vA[16], vB[16];
  float ar = 0.f, ai = 0.f;
  int ni = 0;

#define LOADRECS(base_, recs_)                                        \
  do {                                                                \
    if ((base_) + 16 <= total) {                                      \
      _Pragma("unroll") for (int j = 0; j < 16; ++j)                  \
          (recs_)[j] = crec[ebeg + (base_) + j];                      \
    } else {                                                          \
      _Pragma("unroll") for (int j = 0; j < 16; ++j) {                \
        int idx_ = ((base_) + j < total) ? ebeg + (base_) + j : ebeg; \
        (recs_)[j] = crec[idx_];                                      \
      }                                                               \
    }                                                                 \
  } while (0)

#define ISSUEV(recs_, v_)                                                  \
  do {                                                                     \
    _Pragma("unroll") for (int j = 0; j < 16; ++j)                         \
        (v_)[j] = tbl[(unsigned)((recs_)[j].x & 0x0FFFFFFFu) * 64u + lane]; \
  } while (0)

#define FLUSHTO(nrel_)                      \
  while (ni < (nrel_)) {                    \
    s_ar[ni * LW + lane] = (_Float16)ar;    \
    s_ai[ni * LW + lane] = (_Float16)ai;    \
    ar = 0.f;                               \
    ai = 0.f;                               \
    ++ni;                                   \
  }

#define CONSUME(recs_, v_, base_)                               \
  do {                                                          \
    _Pragma("unroll") for (int j = 0; j < 16; ++j) {            \
      if ((base_) + j >= total) break;                          \
      int nrel_ = (recs_)[j].x >> 28;                           \
      FLUSHTO(nrel_);                                           \
      float2 val_ = unpackh2((v_)[j]);                          \
      float2 wv_ = unpackh2((recs_)[j].y);                      \
      ar = fmaf(wv_.x, val_.x, fmaf(-wv_.y, val_.y, ar));       \
      ai = fmaf(wv_.y, val_.x, fmaf(wv_.x, val_.y, ai));        \
    }                                                           \
  } while (0)

  int nbatch = (total + 15) >> 4;
  if (nbatch > 0) {
    LOADRECS(0, rA);
    ISSUEV(rA, vA);
    if (nbatch > 1) LOADRECS(16, rB);
    for (int b = 0; b < nbatch; b += 2) {
      if (b + 1 < nbatch) ISSUEV(rB, vB);
      CONSUME(rA, vA, b * 16);
      if (b + 2 < nbatch) LOADRECS((b + 2) * 16, rA);
      if (b + 1 < nbatch) {
        if (b + 2 < nbatch) ISSUEV(rA, vA);
        CONSUME(rB, vB, (b + 1) * 16);
        if (b + 3 < nbatch) LOADRECS((b + 3) * 16, rB);
      }
    }
  }
  FLUSHTO(16);
#undef LOADRECS
#undef ISSUEV
#undef FLUSHTO
#undef CONSUME

  half8 a_r[2], a_i[2];
#pragma unroll
  for (int ks = 0; ks < 2; ++ks) {
    int off = c16 * LW + ks * 32 + q16 * 8;
    a_r[ks] = *(const half8*)&s_ar[off];
    a_i[ks] = *(const half8*)&s_ai[off];
  }
  AccRI acc;
#pragma unroll
  for (int nt = 0; nt < 4; ++nt) {
    acc.r[nt] = (f32x4){0.f, 0.f, 0.f, 0.f};
    acc.i[nt] = (f32x4){0.f, 0.f, 0.f, 0.f};
  }
#pragma unroll
  for (int nt = 0; nt < 4; ++nt)
#pragma unroll
    for (int ks = 0; ks < 2; ++ks) {
      half8 b = *(const half8*)&sW[(nt * 16 + c16) * LW + ks * 32 + q16 * 8];
      acc.r[nt] = __builtin_amdgcn_mfma_f32_16x16x32_f16(a_r[ks], b, acc.r[nt], 0, 0, 0);
      acc.i[nt] = __builtin_amdgcn_mfma_f32_16x16x32_f16(a_i[ks], b, acc.i[nt], 0, 0, 0);
    }
  return acc;
}

// ---- layer 1 (8 waves/block, static group map, weight LDS) ----------------
__global__ void __launch_bounds__(512, 6) layer1_k(
    const unsigned* __restrict__ xc,
    const int* __restrict__ offs, const int* __restrict__ cnt,
    const uint2* __restrict__ crec,
    const float* __restrict__ W, const float* __restrict__ bias,
    unsigned* __restrict__ Hc, int N) {
  __shared__ __align__(16) _Float16 sW[64 * LW];
  __shared__ __align__(16) _Float16 s_act[8][2][16 * LW];
  for (int i = threadIdx.x; i < 64 * 64; i += 512)
    sW[(i >> 6) * LW + (i & 63)] = (_Float16)W[i];
  __syncthreads();
  const int w = threadIdx.x >> 6, lane = threadIdx.x & 63;
  const int c16 = lane & 15, q16 = lane >> 4;
  int n0 = (blockIdx.x * 8 + w) * 16;
  if (n0 >= N) return;
  float bl[4];
#pragma unroll
  for (int nt = 0; nt < 4; ++nt) bl[nt] = 2.f * bias[nt * 16 + c16];

  AccRI acc = spmm_gemv(xc, offs, cnt, crec, sW,
                        &s_act[w][0][0], &s_act[w][1][0], n0, N, lane);
#pragma unroll
  for (int nt = 0; nt < 4; ++nt)
#pragma unroll
    for (int r = 0; r < 4; ++r) {
      int node = n0 + q16 * 4 + r;
      if (node < N) {
        float hr = fmaxf(acc.r[nt][r], 0.f);
        float hi = fmaxf(acc.i[nt][r] + bl[nt], 0.f);
        Hc[(unsigned)node * 64u + nt * 16 + c16] = packh2(hr, hi);
      }
    }
}

// ---- layer 2 + final [16x128] projection (8 waves/block) ------------------
__global__ void __launch_bounds__(512, 6) layer2_k(
    const unsigned* __restrict__ Hc,
    const int* __restrict__ offs, const int* __restrict__ cnt,
    const uint2* __restrict__ crec,
    const float* __restrict__ W2, const float* __restrict__ b2,
    const float* __restrict__ W3, const float* __restrict__ b3,
    float* __restrict__ out, int N) {
  __shared__ __align__(16) _Float16 sW[64 * LW];
  __shared__ __align__(16) _Float16 sW3p[16 * LW3];
  __shared__ __align__(16) _Float16 s_act[8][2][16 * LW];
  for (int i = threadIdx.x; i < 64 * 64; i += 512)
    sW[(i >> 6) * LW + (i & 63)] = (_Float16)W2[i];
  // interleaved k' = 2f + (0:real,1:imag)  ->  source W3[o][f + 64*ri]
  for (int i = threadIdx.x; i < 16 * 128; i += 512) {
    int o = i >> 7, kp = i & 127;
    sW3p[o * LW3 + kp] = (_Float16)W3[o * 128 + (kp >> 1) + 64 * (kp & 1)];
  }
  __syncthreads();
  const int w = threadIdx.x >> 6, lane = threadIdx.x & 63;
  const int c16 = lane & 15, q16 = lane >> 4;
  int n0 = (blockIdx.x * 8 + w) * 16;
  if (n0 >= N) return;
  float bl[4];
#pragma unroll
  for (int nt = 0; nt < 4; ++nt) bl[nt] = 2.f * b2[nt * 16 + c16];
  const float b3v = b3[c16];

  AccRI acc = spmm_gemv(Hc, offs, cnt, crec, sW,
                        &s_act[w][0][0], &s_act[w][1][0], n0, N, lane);

  // stage h packed (r,i) per feature into proj buffer (reuses act LDS)
  unsigned* pb = (unsigned*)&s_act[w][0][0];  // [16][68] u32 rows = 136 halves
#pragma unroll
  for (int nt = 0; nt < 4; ++nt)
#pragma unroll
    for (int r = 0; r < 4; ++r) {
      float hr = fmaxf(acc.r[nt][r], 0.f);
      float hi = fmaxf(acc.i[nt][r] + bl[nt], 0.f);
      pb[(q16 * 4 + r) * 68 + nt * 16 + c16] = packh2(hr, hi);
    }
  f32x4 po = {0.f, 0.f, 0.f, 0.f};
#pragma unroll
  for (int ks = 0; ks < 4; ++ks) {
    half8 a = *(const half8*)((const _Float16*)pb + c16 * LW3 + ks * 32 + q16 * 8);
    half8 b = *(const half8*)&sW3p[c16 * LW3 + ks * 32 + q16 * 8];
    po = __builtin_amdgcn_mfma_f32_16x16x32_f16(a, b, po, 0, 0, 0);
  }
#pragma unroll
  for (int r = 0; r < 4; ++r) {
    int node = n0 + q16 * 4 + r;
    if (node < N) out[(unsigned)node * 16u + c16] = po[r] + b3v;
  }
}

extern "C" void kernel_launch(void* const* d_in, const int* in_sizes, int n_in,
                              void* d_out, int out_size, void* d_ws, size_t ws_size,
                              hipStream_t stream) {
  const float* xr   = (const float*)d_in[0];
  const float* xi   = (const float*)d_in[1];
  const float* wsym = (const float*)d_in[2];
  const float* qp   = (const float*)d_in[3];
  const float* ent  = (const float*)d_in[4];
  const float* cc   = (const float*)d_in[5];
  const float* W1   = (const float*)d_in[6];
  const float* b1   = (const float*)d_in[7];
  const float* W2   = (const float*)d_in[8];
  const float* b2   = (const float*)d_in[9];
  const float* W3   = (const float*)d_in[10];
  const float* b3   = (const float*)d_in[11];
  const int*   row  = (const int*)d_in[12];
  const int*   col  = (const int*)d_in[13];
  const int N = in_sizes[0] / 64;
  const int E = in_sizes[2];
  float* out = (float*)d_out;

  char* ws = (char*)d_ws;
  size_t off = 0;
  auto alloc = [&](size_t bytes) -> void* {
    void* p = ws + off;
    off += (bytes + 255) & ~(size_t)255;
    return p;
  };
  int*      cnt    = (int*)alloc((size_t)N * 4);
  int*      offs   = (int*)alloc((size_t)N * 4);
  int*      cursor = (int*)alloc((size_t)N * 4);
  int*      total  = (int*)alloc(256);
  int*      gcur   = (int*)alloc((size_t)NBKTMAX * 4);
  uint2*    crec   = (uint2*)alloc((size_t)E * 8);
  unsigned* xc     = (unsigned*)alloc((size_t)N * 64 * 4);
  unsigned* Hc     = (unsigned*)alloc((size_t)N * 64 * 4);
  uint2*    tmp    = (uint2*)Hc;  // alias: tmp dead before layer1 writes Hc

  hipMemsetAsync(cnt, 0, (size_t)N * 4, stream);
  hipMemsetAsync(total, 0, 256, stream);
  int n4 = N * 64 / 4;
  int npre = (n4 > E ? n4 : E);
  prep_k<<<(npre + 255) / 256, 256, 0, stream>>>((const float4*)xr, (const float4*)xi,
                                                 (uint4*)xc, n4, row, cnt, E);
  int nch = (N + 255) / 256;  // == nbkt
  offs_k<<<(nch + 3) / 4, 256, 0, stream>>>(cnt, offs, cursor, total, gcur, N, nch);
  int ntiles = (E + 2047) / 2048;
  bin_k<<<ntiles, 256, 0, stream>>>(row, col, wsym, qp, ent, cc, gcur, tmp,
                                    E, nch, ntiles);
  fine_k<<<nch, 256, 0, stream>>>(tmp, offs, cnt, cursor, crec, N);
  int nb = (N + 127) / 128;  // 8 waves/block x 16 nodes/wave, static map
  layer1_k<<<nb, 512, 0, stream>>>(xc, offs, cnt, crec, W1, b1, Hc, N);
  layer2_k<<<nb, 512, 0, stream>>>(Hc, offs, cnt, crec, W2, b2, W3, b3, out, N);
}

// Round 10
// 198.551 us; speedup vs baseline: 2.2634x; 1.0806x over previous
//
#include <hip/hip_runtime.h>
#include <hip/hip_fp16.h>

// ---------------------------------------------------------------------------
// Complex 2-layer MAP graph conv. Round 10:
//  - layers: unchanged (512-thr, weight LDS, static group map, 16-deep
//    double-buffered streaming gather, fp16 MFMA GEMV) -- at compulsory-miss
//    memory floor (~2 TB/s L2-miss, occupancy-insensitive).
//  - build: fine_k now uses LDS bases+fill counters (no global cursor
//    atomics, cursor array deleted); bin_k uses fast __sinf/__cosf.
// ---------------------------------------------------------------------------

typedef __attribute__((ext_vector_type(8))) _Float16 half8;
typedef __attribute__((ext_vector_type(4))) float f32x4;

#define LW 72    // LDS act/weight row stride (halves): 144B rows, 16B-aligned
#define LW3 136  // LDS proj row stride (halves): 272B rows
#define NBKTMAX 400  // max 256-node chunks (N <= 102400)
#define CAP 16       // LDS records per bucket per tile

__device__ __forceinline__ unsigned short hbits(float f) {
  return __half_as_ushort(__float2half_rn(f));
}
__device__ __forceinline__ unsigned packh2(float a, float b) {
  return ((unsigned)hbits(b) << 16) | (unsigned)hbits(a);
}
__device__ __forceinline__ float2 unpackh2(unsigned u) {
  __half2 h = *reinterpret_cast<__half2*>(&u);
  return __half22float2(h);
}

// ---- fused feature-pack + row histogram -----------------------------------
__global__ void prep_k(const float4* __restrict__ xr, const float4* __restrict__ xi,
                       uint4* __restrict__ xc, int n4,
                       const int* __restrict__ row, int* __restrict__ cnt, int E) {
  int i = blockIdx.x * 256 + threadIdx.x;
  if (i < E) atomicAdd(&cnt[row[i]], 1);
  if (i < n4) {
    float4 r = xr[i], m = xi[i];
    xc[i] = make_uint4(packh2(r.x, m.x), packh2(r.y, m.y),
                       packh2(r.z, m.z), packh2(r.w, m.w));
  }
}

// ---- 256-node chunk scan: offs + chunk base (gcur) ------------------------
__global__ void offs_k(const int* __restrict__ cnt, int* __restrict__ offs,
                       int* __restrict__ total,
                       int* __restrict__ gcur, int N, int nch) {
  int ch = blockIdx.x * 4 + (threadIdx.x >> 6);
  if (ch >= nch) return;
  int lane = threadIdx.x & 63;
  int n0 = ch * 256 + lane * 4;
  int v0 = 0, v1 = 0, v2 = 0, v3 = 0;
  if (n0 + 3 < N) {
    int4 v = *(const int4*)&cnt[n0];
    v0 = v.x; v1 = v.y; v2 = v.z; v3 = v.w;
  } else {
    if (n0 + 0 < N) v0 = cnt[n0 + 0];
    if (n0 + 1 < N) v1 = cnt[n0 + 1];
    if (n0 + 2 < N) v2 = cnt[n0 + 2];
    if (n0 + 3 < N) v3 = cnt[n0 + 3];
  }
  int s = v0 + v1 + v2 + v3;
  int x = s;
#pragma unroll
  for (int d = 1; d < 64; d <<= 1) {
    int t = __shfl_up(x, d);
    if (lane >= d) x += t;
  }
  int excl = x - s;
  int wtot = __shfl(x, 63);
  int base = 0;
  if (lane == 63) base = atomicAdd(total, wtot);
  base = __shfl(base, 63);
  if (lane == 0) gcur[ch] = base;
  int e0 = base + excl;
  if (n0 + 0 < N) offs[n0 + 0] = e0;
  if (n0 + 1 < N) offs[n0 + 1] = e0 + v0;
  if (n0 + 2 < N) offs[n0 + 2] = e0 + v0 + v1;
  if (n0 + 3 < N) offs[n0 + 3] = e0 + v0 + v1 + v2;
}

// ---- pass 1: bin edges into per-chunk tmp regions (run flushes) -----------
// tmp record: {col | rowLocal<<24, packh2(wr,wi)}
__global__ void __launch_bounds__(256) bin_k(
    const int* __restrict__ row, const int* __restrict__ col,
    const float* __restrict__ wsym, const float* __restrict__ qp,
    const float* __restrict__ ent, const float* __restrict__ cc,
    int* __restrict__ gcur, uint2* __restrict__ tmp,
    int E, int nbkt, int ntiles) {
  __shared__ int lcnt[NBKTMAX];
  __shared__ int lgp[NBKTMAX];
  __shared__ uint2 lbuf[NBKTMAX * CAP];
  const float q = qp[0];
  for (int t = blockIdx.x; t < ntiles; t += gridDim.x) {
    for (int i = threadIdx.x; i < nbkt; i += 256) lcnt[i] = 0;
    __syncthreads();
    int base = t * 2048;
#pragma unroll
    for (int j = 0; j < 8; ++j) {
      int e = base + j * 256 + threadIdx.x;
      if (e < E) {
        float ph = q * (ent[e] + cc[e]);
        float s = __sinf(ph), c = __cosf(ph);
        float w = wsym[e];
        int r = row[e];
        uint2 rec = make_uint2((unsigned)col[e] | ((unsigned)(r & 255) << 24),
                               packh2(w * c, w * s));
        int b = r >> 8;
        int pos = atomicAdd(&lcnt[b], 1);
        if (pos < CAP) lbuf[b * CAP + pos] = rec;
        else {  // rare overflow: direct store
          int gp = atomicAdd(&gcur[b], 1);
          tmp[gp] = rec;
        }
      }
    }
    __syncthreads();
    for (int b = threadIdx.x; b < nbkt; b += 256) {
      int c = lcnt[b];
      if (c > CAP) c = CAP;
      lgp[b] = (c > 0) ? atomicAdd(&gcur[b], c) : 0;
    }
    __syncthreads();
    int slots = nbkt * CAP;
    for (int i = threadIdx.x; i < slots; i += 256) {
      int b = i >> 4, j = i & (CAP - 1);
      int c = lcnt[b];
      if (c > CAP) c = CAP;
      if (j < c) tmp[lgp[b] + j] = lbuf[i];
    }
    __syncthreads();
  }
}

// ---- pass 2: per-chunk reorder to exact CSR positions (LDS counters) ------
__global__ void __launch_bounds__(256) fine_k(
    const uint2* __restrict__ tmp, const int* __restrict__ offs,
    const int* __restrict__ cnt, uint2* __restrict__ crec, int N) {
  __shared__ int ls[256];
  __shared__ int fill[256];
  int first = blockIdx.x << 8;
  int nlast = first + 256;
  if (nlast > N) nlast = N;
  nlast -= 1;
  int beg = offs[first];
  int end = offs[nlast] + cnt[nlast];
  int tid = threadIdx.x;
  int n = first + tid;
  ls[tid] = (n <= nlast) ? (offs[n] - beg) : 0;
  fill[tid] = 0;
  __syncthreads();
  for (int i = beg + tid; i < end; i += 256) {
    uint2 r = tmp[i];
    int loc = (int)(r.x >> 24);
    unsigned c = r.x & 0xFFFFFFu;
    int pos = beg + ls[loc] + atomicAdd(&fill[loc], 1);
    crec[pos] = make_uint2(c | ((unsigned)(loc & 15) << 28), r.y);
  }
}

// ---- streaming SPMM(16-node group) + MFMA GEMV ----------------------------
// A-frag (16x16x32 f16): lane holds A[lane&15][(lane>>4)*8+j]; A row = node.
// C/D: col(lane&15)=out-feature, row((lane>>4)*4+reg)=node.
struct AccRI {
  f32x4 r[4], i[4];
};

__device__ __forceinline__ AccRI spmm_gemv(
    const unsigned* __restrict__ tbl,
    const int* __restrict__ offs, const int* __restrict__ cnt,
    const uint2* __restrict__ crec,
    const _Float16* __restrict__ sW,
    _Float16* __restrict__ s_ar, _Float16* __restrict__ s_ai,
    int n0, int N, int lane) {
  const int c16 = lane & 15, q16 = lane >> 4;
  int nlast = n0 + 15;
  if (nlast >= N) nlast = N - 1;
  int ebeg = __builtin_amdgcn_readfirstlane(offs[n0]);
  int eend = __builtin_amdgcn_readfirstlane(offs[nlast] + cnt[nlast]);
  int total = eend - ebeg;

  uint2 rA[16], rB[16];
  unsigned vA[16], vB[16];
  float ar = 0.f, ai = 0.f;
  int ni = 0;

#define LOADRECS(base_, recs_)                                        \
  do {                                                                \
    if ((base_) + 16 <= total) {                                      \
      _Pragma("unroll") for (int j = 0; j < 16; ++j)                  \
          (recs_)[j] = crec[ebeg + (base_) + j];                      \
    } else {                                                          \
      _Pragma("unroll") for (int j = 0; j < 16; ++j) {                \
        int idx_ = ((base_) + j < total) ? ebeg + (base_) + j : ebeg; \
        (recs_)[j] = crec[idx_];                                      \
      }                                                               \
    }                                                                 \
  } while (0)

#define ISSUEV(recs_, v_)                                                  \
  do {                                                                     \
    _Pragma("unroll") for (int j = 0; j < 16; ++j)                         \
        (v_)[j] = tbl[(unsigned)((recs_)[j].x & 0x0FFFFFFFu) * 64u + lane]; \
  } while (0)

#define FLUSHTO(nrel_)                      \
  while (ni < (nrel_)) {                    \
    s_ar[ni * LW + lane] = (_Float16)ar;    \
    s_ai[ni * LW + lane] = (_Float16)ai;    \
    ar = 0.f;                               \
    ai = 0.f;                               \
    ++ni;                                   \
  }

#define CONSUME(recs_, v_, base_)                               \
  do {                                                          \
    _Pragma("unroll") for (int j = 0; j < 16; ++j) {            \
      if ((base_) + j >= total) break;                          \
      int nrel_ = (recs_)[j].x >> 28;                           \
      FLUSHTO(nrel_);                                           \
      float2 val_ = unpackh2((v_)[j]);                          \
      float2 wv_ = unpackh2((recs_)[j].y);                      \
      ar = fmaf(wv_.x, val_.x, fmaf(-wv_.y, val_.y, ar));       \
      ai = fmaf(wv_.y, val_.x, fmaf(wv_.x, val_.y, ai));        \
    }                                                           \
  } while (0)

  int nbatch = (total + 15) >> 4;
  if (nbatch > 0) {
    LOADRECS(0, rA);
    ISSUEV(rA, vA);
    if (nbatch > 1) LOADRECS(16, rB);
    for (int b = 0; b < nbatch; b += 2) {
      if (b + 1 < nbatch) ISSUEV(rB, vB);
      CONSUME(rA, vA, b * 16);
      if (b + 2 < nbatch) LOADRECS((b + 2) * 16, rA);
      if (b + 1 < nbatch) {
        if (b + 2 < nbatch) ISSUEV(rA, vA);
        CONSUME(rB, vB, (b + 1) * 16);
        if (b + 3 < nbatch) LOADRECS((b + 3) * 16, rB);
      }
    }
  }
  FLUSHTO(16);
#undef LOADRECS
#undef ISSUEV
#undef FLUSHTO
#undef CONSUME

  half8 a_r[2], a_i[2];
#pragma unroll
  for (int ks = 0; ks < 2; ++ks) {
    int off = c16 * LW + ks * 32 + q16 * 8;
    a_r[ks] = *(const half8*)&s_ar[off];
    a_i[ks] = *(const half8*)&s_ai[off];
  }
  AccRI acc;
#pragma unroll
  for (int nt = 0; nt < 4; ++nt) {
    acc.r[nt] = (f32x4){0.f, 0.f, 0.f, 0.f};
    acc.i[nt] = (f32x4){0.f, 0.f, 0.f, 0.f};
  }
#pragma unroll
  for (int nt = 0; nt < 4; ++nt)
#pragma unroll
    for (int ks = 0; ks < 2; ++ks) {
      half8 b = *(const half8*)&sW[(nt * 16 + c16) * LW + ks * 32 + q16 * 8];
      acc.r[nt] = __builtin_amdgcn_mfma_f32_16x16x32_f16(a_r[ks], b, acc.r[nt], 0, 0, 0);
      acc.i[nt] = __builtin_amdgcn_mfma_f32_16x16x32_f16(a_i[ks], b, acc.i[nt], 0, 0, 0);
    }
  return acc;
}

// ---- layer 1 (8 waves/block, static group map, weight LDS) ----------------
__global__ void __launch_bounds__(512, 6) layer1_k(
    const unsigned* __restrict__ xc,
    const int* __restrict__ offs, const int* __restrict__ cnt,
    const uint2* __restrict__ crec,
    const float* __restrict__ W, const float* __restrict__ bias,
    unsigned* __restrict__ Hc, int N) {
  __shared__ __align__(16) _Float16 sW[64 * LW];
  __shared__ __align__(16) _Float16 s_act[8][2][16 * LW];
  for (int i = threadIdx.x; i < 64 * 64; i += 512)
    sW[(i >> 6) * LW + (i & 63)] = (_Float16)W[i];
  __syncthreads();
  const int w = threadIdx.x >> 6, lane = threadIdx.x & 63;
  const int c16 = lane & 15, q16 = lane >> 4;
  int n0 = (blockIdx.x * 8 + w) * 16;
  if (n0 >= N) return;
  float bl[4];
#pragma unroll
  for (int nt = 0; nt < 4; ++nt) bl[nt] = 2.f * bias[nt * 16 + c16];

  AccRI acc = spmm_gemv(xc, offs, cnt, crec, sW,
                        &s_act[w][0][0], &s_act[w][1][0], n0, N, lane);
#pragma unroll
  for (int nt = 0; nt < 4; ++nt)
#pragma unroll
    for (int r = 0; r < 4; ++r) {
      int node = n0 + q16 * 4 + r;
      if (node < N) {
        float hr = fmaxf(acc.r[nt][r], 0.f);
        float hi = fmaxf(acc.i[nt][r] + bl[nt], 0.f);
        Hc[(unsigned)node * 64u + nt * 16 + c16] = packh2(hr, hi);
      }
    }
}

// ---- layer 2 + final [16x128] projection (8 waves/block) ------------------
__global__ void __launch_bounds__(512, 6) layer2_k(
    const unsigned* __restrict__ Hc,
    const int* __restrict__ offs, const int* __restrict__ cnt,
    const uint2* __restrict__ crec,
    const float* __restrict__ W2, const float* __restrict__ b2,
    const float* __restrict__ W3, const float* __restrict__ b3,
    float* __restrict__ out, int N) {
  __shared__ __align__(16) _Float16 sW[64 * LW];
  __shared__ __align__(16) _Float16 sW3p[16 * LW3];
  __shared__ __align__(16) _Float16 s_act[8][2][16 * LW];
  for (int i = threadIdx.x; i < 64 * 64; i += 512)
    sW[(i >> 6) * LW + (i & 63)] = (_Float16)W2[i];
  // interleaved k' = 2f + (0:real,1:imag)  ->  source W3[o][f + 64*ri]
  for (int i = threadIdx.x; i < 16 * 128; i += 512) {
    int o = i >> 7, kp = i & 127;
    sW3p[o * LW3 + kp] = (_Float16)W3[o * 128 + (kp >> 1) + 64 * (kp & 1)];
  }
  __syncthreads();
  const int w = threadIdx.x >> 6, lane = threadIdx.x & 63;
  const int c16 = lane & 15, q16 = lane >> 4;
  int n0 = (blockIdx.x * 8 + w) * 16;
  if (n0 >= N) return;
  float bl[4];
#pragma unroll
  for (int nt = 0; nt < 4; ++nt) bl[nt] = 2.f * b2[nt * 16 + c16];
  const float b3v = b3[c16];

  AccRI acc = spmm_gemv(Hc, offs, cnt, crec, sW,
                        &s_act[w][0][0], &s_act[w][1][0], n0, N, lane);

  // stage h packed (r,i) per feature into proj buffer (reuses act LDS)
  unsigned* pb = (unsigned*)&s_act[w][0][0];  // [16][68] u32 rows = 136 halves
#pragma unroll
  for (int nt = 0; nt < 4; ++nt)
#pragma unroll
    for (int r = 0; r < 4; ++r) {
      float hr = fmaxf(acc.r[nt][r], 0.f);
      float hi = fmaxf(acc.i[nt][r] + bl[nt], 0.f);
      pb[(q16 * 4 + r) * 68 + nt * 16 + c16] = packh2(hr, hi);
    }
  f32x4 po = {0.f, 0.f, 0.f, 0.f};
#pragma unroll
  for (int ks = 0; ks < 4; ++ks) {
    half8 a = *(const half8*)((const _Float16*)pb + c16 * LW3 + ks * 32 + q16 * 8);
    half8 b = *(const half8*)&sW3p[c16 * LW3 + ks * 32 + q16 * 8];
    po = __builtin_amdgcn_mfma_f32_16x16x32_f16(a, b, po, 0, 0, 0);
  }
#pragma unroll
  for (int r = 0; r < 4; ++r) {
    int node = n0 + q16 * 4 + r;
    if (node < N) out[(unsigned)node * 16u + c16] = po[r] + b3v;
  }
}

extern "C" void kernel_launch(void* const* d_in, const int* in_sizes, int n_in,
                              void* d_out, int out_size, void* d_ws, size_t ws_size,
                              hipStream_t stream) {
  const float* xr   = (const float*)d_in[0];
  const float* xi   = (const float*)d_in[1];
  const float* wsym = (const float*)d_in[2];
  const float* qp   = (const float*)d_in[3];
  const float* ent  = (const float*)d_in[4];
  const float* cc   = (const float*)d_in[5];
  const float* W1   = (const float*)d_in[6];
  const float* b1   = (const float*)d_in[7];
  const float* W2   = (const float*)d_in[8];
  const float* b2   = (const float*)d_in[9];
  const float* W3   = (const float*)d_in[10];
  const float* b3   = (const float*)d_in[11];
  const int*   row  = (const int*)d_in[12];
  const int*   col  = (const int*)d_in[13];
  const int N = in_sizes[0] / 64;
  const int E = in_sizes[2];
  float* out = (float*)d_out;

  char* ws = (char*)d_ws;
  size_t off = 0;
  auto alloc = [&](size_t bytes) -> void* {
    void* p = ws + off;
    off += (bytes + 255) & ~(size_t)255;
    return p;
  };
  int*      cnt    = (int*)alloc((size_t)N * 4);
  int*      offs   = (int*)alloc((size_t)N * 4);
  int*      total  = (int*)alloc(256);
  int*      gcur   = (int*)alloc((size_t)NBKTMAX * 4);
  uint2*    crec   = (uint2*)alloc((size_t)E * 8);
  unsigned* xc     = (unsigned*)alloc((size_t)N * 64 * 4);
  unsigned* Hc     = (unsigned*)alloc((size_t)N * 64 * 4);
  uint2*    tmp    = (uint2*)Hc;  // alias: tmp dead before layer1 writes Hc

  hipMemsetAsync(cnt, 0, (size_t)N * 4, stream);
  hipMemsetAsync(total, 0, 256, stream);
  int n4 = N * 64 / 4;
  int npre = (n4 > E ? n4 : E);
  prep_k<<<(npre + 255) / 256, 256, 0, stream>>>((const float4*)xr, (const float4*)xi,
                                                 (uint4*)xc, n4, row, cnt, E);
  int nch = (N + 255) / 256;  // == nbkt
  offs_k<<<(nch + 3) / 4, 256, 0, stream>>>(cnt, offs, total, gcur, N, nch);
  int ntiles = (E + 2047) / 2048;
  bin_k<<<ntiles, 256, 0, stream>>>(row, col, wsym, qp, ent, cc, gcur, tmp,
                                    E, nch, ntiles);
  fine_k<<<nch, 256, 0, stream>>>(tmp, offs, cnt, crec, N);
  int nb = (N + 127) / 128;  // 8 waves/block x 16 nodes/wave, static map
  layer1_k<<<nb, 512, 0, stream>>>(xc, offs, cnt, crec, W1, b1, Hc, N);
  layer2_k<<<nb, 512, 0, stream>>>(Hc, offs, cnt, crec, W2, b2, W3, b3, out, N);
}

// Round 11
// 171.410 us; speedup vs baseline: 2.6218x; 1.1583x over previous
//
#include <hip/hip_runtime.h>
#include <hip/hip_fp16.h>

// ---------------------------------------------------------------------------
// Complex 2-layer MAP graph conv. Round 11:
//  - layers: unchanged (at compulsory-miss fabric floor, ~2 TB/s random-line)
//    except cnt[] replaced by offs[] sentinel diff.
//  - build rework: 391-entry chunk histogram (LDS-aggregated) replaces the
//    N-sized node histogram; per-node offsets computed inside fine_k via
//    block scan; pack folded into bin_k. 7 dispatches, no big memsets.
// ---------------------------------------------------------------------------

typedef __attribute__((ext_vector_type(8))) _Float16 half8;
typedef __attribute__((ext_vector_type(4))) float f32x4;

#define LW 72    // LDS act/weight row stride (halves): 144B rows, 16B-aligned
#define LW3 136  // LDS proj row stride (halves): 272B rows
#define NBKTMAX 400  // max 256-node chunks (N <= 102400)
#define CAP 16       // LDS records per bucket per tile

__device__ __forceinline__ unsigned short hbits(float f) {
  return __half_as_ushort(__float2half_rn(f));
}
__device__ __forceinline__ unsigned packh2(float a, float b) {
  return ((unsigned)hbits(b) << 16) | (unsigned)hbits(a);
}
__device__ __forceinline__ float2 unpackh2(unsigned u) {
  __half2 h = *reinterpret_cast<__half2*>(&u);
  return __half22float2(h);
}

// ---- chunk histogram (row>>8), LDS-aggregated -----------------------------
__global__ void hist_k(const int* __restrict__ row, int* __restrict__ chcnt,
                       int E, int nch) {
  __shared__ int h[NBKTMAX];
  for (int i = threadIdx.x; i < nch; i += 256) h[i] = 0;
  __syncthreads();
  for (int e = blockIdx.x * 256 + threadIdx.x; e < E; e += gridDim.x * 256)
    atomicAdd(&h[row[e] >> 8], 1);
  __syncthreads();
  for (int i = threadIdx.x; i < nch; i += 256)
    if (h[i]) atomicAdd(&chcnt[i], h[i]);
}

// ---- single-block scan of chunk counts -> chbase (w/ sentinel) + gcur -----
__global__ void cscan_k(const int* __restrict__ chcnt, int* __restrict__ chbase,
                        int* __restrict__ gcur, int nch, int E) {
  __shared__ int buf[512];
  int t = threadIdx.x;
  int v = (t < nch) ? chcnt[t] : 0;
  buf[t] = v;
  __syncthreads();
  for (int d = 1; d < 512; d <<= 1) {
    int y = (t >= d) ? buf[t - d] : 0;
    __syncthreads();
    buf[t] += y;
    __syncthreads();
  }
  int excl = buf[t] - v;
  if (t < nch) {
    chbase[t] = excl;
    gcur[t] = excl;
  }
  if (t == nch) chbase[nch] = E;
}

// ---- pass 1: pack features (prologue) + bin edges into chunk regions ------
// tmp record: {col | rowLocal<<24, packh2(wr,wi)}
__global__ void __launch_bounds__(256) bin_k(
    const float4* __restrict__ xr, const float4* __restrict__ xi,
    uint4* __restrict__ xc, int n4,
    const int* __restrict__ row, const int* __restrict__ col,
    const float* __restrict__ wsym, const float* __restrict__ qp,
    const float* __restrict__ ent, const float* __restrict__ cc,
    int* __restrict__ gcur, uint2* __restrict__ tmp,
    int E, int nbkt, int ntiles) {
  // feature pack (independent of binning; grid-stride)
  for (int i = blockIdx.x * 256 + threadIdx.x; i < n4; i += gridDim.x * 256) {
    float4 r = xr[i], m = xi[i];
    xc[i] = make_uint4(packh2(r.x, m.x), packh2(r.y, m.y),
                       packh2(r.z, m.z), packh2(r.w, m.w));
  }
  __shared__ int lcnt[NBKTMAX];
  __shared__ int lgp[NBKTMAX];
  __shared__ uint2 lbuf[NBKTMAX * CAP];
  const float q = qp[0];
  for (int t = blockIdx.x; t < ntiles; t += gridDim.x) {
    for (int i = threadIdx.x; i < nbkt; i += 256) lcnt[i] = 0;
    __syncthreads();
    int base = t * 2048;
#pragma unroll
    for (int j = 0; j < 8; ++j) {
      int e = base + j * 256 + threadIdx.x;
      if (e < E) {
        float ph = q * (ent[e] + cc[e]);
        float s = __sinf(ph), c = __cosf(ph);
        float w = wsym[e];
        int r = row[e];
        uint2 rec = make_uint2((unsigned)col[e] | ((unsigned)(r & 255) << 24),
                               packh2(w * c, w * s));
        int b = r >> 8;
        int pos = atomicAdd(&lcnt[b], 1);
        if (pos < CAP) lbuf[b * CAP + pos] = rec;
        else {  // rare overflow: direct store
          int gp = atomicAdd(&gcur[b], 1);
          tmp[gp] = rec;
        }
      }
    }
    __syncthreads();
    for (int b = threadIdx.x; b < nbkt; b += 256) {
      int c = lcnt[b];
      if (c > CAP) c = CAP;
      lgp[b] = (c > 0) ? atomicAdd(&gcur[b], c) : 0;
    }
    __syncthreads();
    int slots = nbkt * CAP;
    for (int i = threadIdx.x; i < slots; i += 256) {
      int b = i >> 4, j = i & (CAP - 1);
      int c = lcnt[b];
      if (c > CAP) c = CAP;
      if (j < c) tmp[lgp[b] + j] = lbuf[i];
    }
    __syncthreads();
  }
}

// ---- pass 2: per-chunk reorder + per-node offset computation --------------
__global__ void __launch_bounds__(256) fine_k(
    const uint2* __restrict__ tmp, const int* __restrict__ chbase,
    int* __restrict__ offs, uint2* __restrict__ crec, int N) {
  __shared__ int cntl[256];
  __shared__ int ls[256];
  __shared__ int fill[256];
  __shared__ int buf[256];
  int tid = threadIdx.x;
  int ch = blockIdx.x;
  int first = ch << 8;
  int beg = chbase[ch];
  int end = chbase[ch + 1];
  cntl[tid] = 0;
  fill[tid] = 0;
  __syncthreads();
  for (int i = beg + tid; i < end; i += 256)
    atomicAdd(&cntl[tmp[i].x >> 24], 1);
  __syncthreads();
  int v = cntl[tid];
  buf[tid] = v;
  __syncthreads();
  for (int d = 1; d < 256; d <<= 1) {
    int y = (tid >= d) ? buf[tid - d] : 0;
    __syncthreads();
    buf[tid] += y;
    __syncthreads();
  }
  int excl = buf[tid] - v;
  ls[tid] = excl;
  int n = first + tid;
  if (n < N) offs[n] = beg + excl;
  if (tid == 0 && ch == gridDim.x - 1) offs[N] = end;
  __syncthreads();
  for (int i = beg + tid; i < end; i += 256) {
    uint2 r = tmp[i];
    int loc = (int)(r.x >> 24);
    unsigned c = r.x & 0xFFFFFFu;
    int pos = beg + ls[loc] + atomicAdd(&fill[loc], 1);
    crec[pos] = make_uint2(c | ((unsigned)(loc & 15) << 28), r.y);
  }
}

// ---- streaming SPMM(16-node group) + MFMA GEMV ----------------------------
// A-frag (16x16x32 f16): lane holds A[lane&15][(lane>>4)*8+j]; A row = node.
// C/D: col(lane&15)=out-feature, row((lane>>4)*4+reg)=node.
struct AccRI {
  f32x4 r[4], i[4];
};

__device__ __forceinline__ AccRI spmm_gemv(
    const unsigned* __restrict__ tbl,
    const int* __restrict__ offs,
    const uint2* __restrict__ crec,
    const _Float16* __restrict__ sW,
    _Float16* __restrict__ s_ar, _Float16* __restrict__ s_ai,
    int n0, int N, int lane) {
  const int c16 = lane & 15, q16 = lane >> 4;
  int nend = n0 + 16;
  if (nend > N) nend = N;
  int ebeg = __builtin_amdgcn_readfirstlane(offs[n0]);
  int eend = __builtin_amdgcn_readfirstlane(offs[nend]);
  int total = eend - ebeg;

  uint2 rA[16], rB[16];
  unsigned vA[16], vB[16];
  float ar = 0.f, ai = 0.f;
  int ni = 0;

#define LOADRECS(base_, recs_)                                        \
  do {                                                                \
    if ((base_) + 16 <= total) {                                      \
      _Pragma("unroll") for (int j = 0; j < 16; ++j)                  \
          (recs_)[j] = crec[ebeg + (base_) + j];                      \
    } else {                                                          \
      _Pragma("unroll") for (int j = 0; j < 16; ++j) {                \
        int idx_ = ((base_) + j < total) ? ebeg + (base_) + j : ebeg; \
        (recs_)[j] = crec[idx_];                                      \
      }                                                               \
    }                                                                 \
  } while (0)

#define ISSUEV(recs_, v_)                                                  \
  do {                                                                     \
    _Pragma("unroll") for (int j = 0; j < 16; ++j)                         \
        (v_)[j] = tbl[(unsigned)((recs_)[j].x & 0x0FFFFFFFu) * 64u + lane]; \
  } while (0)

#define FLUSHTO(nrel_)                      \
  while (ni < (nrel_)) {                    \
    s_ar[ni * LW + lane] = (_Float16)ar;    \
    s_ai[ni * LW + lane] = (_Float16)ai;    \
    ar = 0.f;                               \
    ai = 0.f;                               \
    ++ni;                                   \
  }

#define CONSUME(recs_, v_, base_)                               \
  do {                                                          \
    _Pragma("unroll") for (int j = 0; j < 16; ++j) {            \
      if ((base_) + j >= total) break;                          \
      int nrel_ = (recs_)[j].x >> 28;                           \
      FLUSHTO(nrel_);                                           \
      float2 val_ = unpackh2((v_)[j]);                          \
      float2 wv_ = unpackh2((recs_)[j].y);                      \
      ar = fmaf(wv_.x, val_.x, fmaf(-wv_.y, val_.y, ar));       \
      ai = fmaf(wv_.y, val_.x, fmaf(wv_.x, val_.y, ai));        \
    }                                                           \
  } while (0)

  int nbatch = (total + 15) >> 4;
  if (nbatch > 0) {
    LOADRECS(0, rA);
    ISSUEV(rA, vA);
    if (nbatch > 1) LOADRECS(16, rB);
    for (int b = 0; b < nbatch; b += 2) {
      if (b + 1 < nbatch) ISSUEV(rB, vB);
      CONSUME(rA, vA, b * 16);
      if (b + 2 < nbatch) LOADRECS((b + 2) * 16, rA);
      if (b + 1 < nbatch) {
        if (b + 2 < nbatch) ISSUEV(rA, vA);
        CONSUME(rB, vB, (b + 1) * 16);
        if (b + 3 < nbatch) LOADRECS((b + 3) * 16, rB);
      }
    }
  }
  FLUSHTO(16);
#undef LOADRECS
#undef ISSUEV
#undef FLUSHTO
#undef CONSUME

  half8 a_r[2], a_i[2];
#pragma unroll
  for (int ks = 0; ks < 2; ++ks) {
    int off = c16 * LW + ks * 32 + q16 * 8;
    a_r[ks] = *(const half8*)&s_ar[off];
    a_i[ks] = *(const half8*)&s_ai[off];
  }
  AccRI acc;
#pragma unroll
  for (int nt = 0; nt < 4; ++nt) {
    acc.r[nt] = (f32x4){0.f, 0.f, 0.f, 0.f};
    acc.i[nt] = (f32x4){0.f, 0.f, 0.f, 0.f};
  }
#pragma unroll
  for (int nt = 0; nt < 4; ++nt)
#pragma unroll
    for (int ks = 0; ks < 2; ++ks) {
      half8 b = *(const half8*)&sW[(nt * 16 + c16) * LW + ks * 32 + q16 * 8];
      acc.r[nt] = __builtin_amdgcn_mfma_f32_16x16x32_f16(a_r[ks], b, acc.r[nt], 0, 0, 0);
      acc.i[nt] = __builtin_amdgcn_mfma_f32_16x16x32_f16(a_i[ks], b, acc.i[nt], 0, 0, 0);
    }
  return acc;
}

// ---- layer 1 (8 waves/block, static group map, weight LDS) ----------------
__global__ void __launch_bounds__(512, 6) layer1_k(
    const unsigned* __restrict__ xc,
    const int* __restrict__ offs,
    const uint2* __restrict__ crec,
    const float* __restrict__ W, const float* __restrict__ bias,
    unsigned* __restrict__ Hc, int N) {
  __shared__ __align__(16) _Float16 sW[64 * LW];
  __shared__ __align__(16) _Float16 s_act[8][2][16 * LW];
  for (int i = threadIdx.x; i < 64 * 64; i += 512)
    sW[(i >> 6) * LW + (i & 63)] = (_Float16)W[i];
  __syncthreads();
  const int w = threadIdx.x >> 6, lane = threadIdx.x & 63;
  const int c16 = lane & 15, q16 = lane >> 4;
  int n0 = (blockIdx.x * 8 + w) * 16;
  if (n0 >= N) return;
  float bl[4];
#pragma unroll
  for (int nt = 0; nt < 4; ++nt) bl[nt] = 2.f * bias[nt * 16 + c16];

  AccRI acc = spmm_gemv(xc, offs, crec, sW,
                        &s_act[w][0][0], &s_act[w][1][0], n0, N, lane);
#pragma unroll
  for (int nt = 0; nt < 4; ++nt)
#pragma unroll
    for (int r = 0; r < 4; ++r) {
      int node = n0 + q16 * 4 + r;
      if (node < N) {
        float hr = fmaxf(acc.r[nt][r], 0.f);
        float hi = fmaxf(acc.i[nt][r] + bl[nt], 0.f);
        Hc[(unsigned)node * 64u + nt * 16 + c16] = packh2(hr, hi);
      }
    }
}

// ---- layer 2 + final [16x128] projection (8 waves/block) ------------------
__global__ void __launch_bounds__(512, 6) layer2_k(
    const unsigned* __restrict__ Hc,
    const int* __restrict__ offs,
    const uint2* __restrict__ crec,
    const float* __restrict__ W2, const float* __restrict__ b2,
    const float* __restrict__ W3, const float* __restrict__ b3,
    float* __restrict__ out, int N) {
  __shared__ __align__(16) _Float16 sW[64 * LW];
  __shared__ __align__(16) _Float16 sW3p[16 * LW3];
  __shared__ __align__(16) _Float16 s_act[8][2][16 * LW];
  for (int i = threadIdx.x; i < 64 * 64; i += 512)
    sW[(i >> 6) * LW + (i & 63)] = (_Float16)W2[i];
  // interleaved k' = 2f + (0:real,1:imag)  ->  source W3[o][f + 64*ri]
  for (int i = threadIdx.x; i < 16 * 128; i += 512) {
    int o = i >> 7, kp = i & 127;
    sW3p[o * LW3 + kp] = (_Float16)W3[o * 128 + (kp >> 1) + 64 * (kp & 1)];
  }
  __syncthreads();
  const int w = threadIdx.x >> 6, lane = threadIdx.x & 63;
  const int c16 = lane & 15, q16 = lane >> 4;
  int n0 = (blockIdx.x * 8 + w) * 16;
  if (n0 >= N) return;
  float bl[4];
#pragma unroll
  for (int nt = 0; nt < 4; ++nt) bl[nt] = 2.f * b2[nt * 16 + c16];
  const float b3v = b3[c16];

  AccRI acc = spmm_gemv(Hc, offs, crec, sW,
                        &s_act[w][0][0], &s_act[w][1][0], n0, N, lane);

  // stage h packed (r,i) per feature into proj buffer (reuses act LDS)
  unsigned* pb = (unsigned*)&s_act[w][0][0];  // [16][68] u32 rows = 136 halves
#pragma unroll
  for (int nt = 0; nt < 4; ++nt)
#pragma unroll
    for (int r = 0; r < 4; ++r) {
      float hr = fmaxf(acc.r[nt][r], 0.f);
      float hi = fmaxf(acc.i[nt][r] + bl[nt], 0.f);
      pb[(q16 * 4 + r) * 68 + nt * 16 + c16] = packh2(hr, hi);
    }
  f32x4 po = {0.f, 0.f, 0.f, 0.f};
#pragma unroll
  for (int ks = 0; ks < 4; ++ks) {
    half8 a = *(const half8*)((const _Float16*)pb + c16 * LW3 + ks * 32 + q16 * 8);
    half8 b = *(const half8*)&sW3p[c16 * LW3 + ks * 32 + q16 * 8];
    po = __builtin_amdgcn_mfma_f32_16x16x32_f16(a, b, po, 0, 0, 0);
  }
#pragma unroll
  for (int r = 0; r < 4; ++r) {
    int node = n0 + q16 * 4 + r;
    if (node < N) out[(unsigned)node * 16u + c16] = po[r] + b3v;
  }
}

extern "C" void kernel_launch(void* const* d_in, const int* in_sizes, int n_in,
                              void* d_out, int out_size, void* d_ws, size_t ws_size,
                              hipStream_t stream) {
  const float* xr   = (const float*)d_in[0];
  const float* xi   = (const float*)d_in[1];
  const float* wsym = (const float*)d_in[2];
  const float* qp   = (const float*)d_in[3];
  const float* ent  = (const float*)d_in[4];
  const float* cc   = (const float*)d_in[5];
  const float* W1   = (const float*)d_in[6];
  const float* b1   = (const float*)d_in[7];
  const float* W2   = (const float*)d_in[8];
  const float* b2   = (const float*)d_in[9];
  const float* W3   = (const float*)d_in[10];
  const float* b3   = (const float*)d_in[11];
  const int*   row  = (const int*)d_in[12];
  const int*   col  = (const int*)d_in[13];
  const int N = in_sizes[0] / 64;
  const int E = in_sizes[2];
  float* out = (float*)d_out;

  char* ws = (char*)d_ws;
  size_t off = 0;
  auto alloc = [&](size_t bytes) -> void* {
    void* p = ws + off;
    off += (bytes + 255) & ~(size_t)255;
    return p;
  };
  int*      chcnt  = (int*)alloc((size_t)NBKTMAX * 4);
  int*      chbase = (int*)alloc((size_t)(NBKTMAX + 1) * 4);
  int*      gcur   = (int*)alloc((size_t)NBKTMAX * 4);
  int*      offs   = (int*)alloc((size_t)(N + 1) * 4);
  uint2*    crec   = (uint2*)alloc((size_t)E * 8);
  unsigned* xc     = (unsigned*)alloc((size_t)N * 64 * 4);
  unsigned* Hc     = (unsigned*)alloc((size_t)N * 64 * 4);
  uint2*    tmp    = (uint2*)Hc;  // alias: tmp dead before layer1 writes Hc

  hipMemsetAsync(chcnt, 0, (size_t)NBKTMAX * 4, stream);
  int nch = (N + 255) / 256;  // == nbkt (<= NBKTMAX)
  int ntiles = (E + 2047) / 2048;
  hist_k<<<ntiles, 256, 0, stream>>>(row, chcnt, E, nch);
  cscan_k<<<1, 512, 0, stream>>>(chcnt, chbase, gcur, nch, E);
  int n4 = N * 64 / 4;
  bin_k<<<ntiles, 256, 0, stream>>>((const float4*)xr, (const float4*)xi,
                                    (uint4*)xc, n4, row, col, wsym, qp, ent, cc,
                                    gcur, tmp, E, nch, ntiles);
  fine_k<<<nch, 256, 0, stream>>>(tmp, chbase, offs, crec, N);
  int nb = (N + 127) / 128;  // 8 waves/block x 16 nodes/wave, static map
  layer1_k<<<nb, 512, 0, stream>>>(xc, offs, crec, W1, b1, Hc, N);
  layer2_k<<<nb, 512, 0, stream>>>(Hc, offs, crec, W2, b2, W3, b3, out, N);
}

// Round 12
// 165.920 us; speedup vs baseline: 2.7085x; 1.0331x over previous
//
#include <hip/hip_runtime.h>
#include <hip/hip_fp16.h>

// ---------------------------------------------------------------------------
// Complex 2-layer MAP graph conv. Round 12:
//  - layers: unchanged (gather at compulsory-miss fabric floor ~2 TB/s,
//    A/B-verified occupancy-insensitive).
//  - build: memset + global-atomic chunk histogram replaced by per-block
//    partial histogram rows (hist_k, fully written -> no init) summed in
//    cscan_k. 6 dispatches, zero memsets.
// ---------------------------------------------------------------------------

typedef __attribute__((ext_vector_type(8))) _Float16 half8;
typedef __attribute__((ext_vector_type(4))) float f32x4;

#define LW 72    // LDS act/weight row stride (halves): 144B rows, 16B-aligned
#define LW3 136  // LDS proj row stride (halves): 272B rows
#define NBKTMAX 400  // max 256-node chunks (N <= 102400)
#define CAP 16       // LDS records per bucket per tile
#define HBLK 256     // hist_k blocks (partial-histogram rows)

__device__ __forceinline__ unsigned short hbits(float f) {
  return __half_as_ushort(__float2half_rn(f));
}
__device__ __forceinline__ unsigned packh2(float a, float b) {
  return ((unsigned)hbits(b) << 16) | (unsigned)hbits(a);
}
__device__ __forceinline__ float2 unpackh2(unsigned u) {
  __half2 h = *reinterpret_cast<__half2*>(&u);
  return __half22float2(h);
}

// ---- chunk histogram (row>>8): per-block partial rows, no init needed -----
__global__ void __launch_bounds__(256) hist_k(
    const int* __restrict__ row, int* __restrict__ hist_part, int E, int nch) {
  __shared__ int h[NBKTMAX];
  for (int i = threadIdx.x; i < nch; i += 256) h[i] = 0;
  __syncthreads();
  for (int e = blockIdx.x * 256 + threadIdx.x; e < E; e += HBLK * 256)
    atomicAdd(&h[row[e] >> 8], 1);
  __syncthreads();
  for (int i = threadIdx.x; i < nch; i += 256)
    hist_part[blockIdx.x * NBKTMAX + i] = h[i];
}

// ---- single-block: sum partial rows, scan -> chbase (w/ sentinel) + gcur --
__global__ void __launch_bounds__(512) cscan_k(
    const int* __restrict__ hist_part, int* __restrict__ chbase,
    int* __restrict__ gcur, int nch, int E) {
  __shared__ int buf[512];
  int t = threadIdx.x;
  int v = 0;
  if (t < nch)
    for (int b = 0; b < HBLK; ++b) v += hist_part[b * NBKTMAX + t];
  buf[t] = v;
  __syncthreads();
  for (int d = 1; d < 512; d <<= 1) {
    int y = (t >= d) ? buf[t - d] : 0;
    __syncthreads();
    buf[t] += y;
    __syncthreads();
  }
  int excl = buf[t] - v;
  if (t < nch) {
    chbase[t] = excl;
    gcur[t] = excl;
  }
  if (t == nch) chbase[nch] = E;
}

// ---- pass 1: pack features (prologue) + bin edges into chunk regions ------
// tmp record: {col | rowLocal<<24, packh2(wr,wi)}
__global__ void __launch_bounds__(256) bin_k(
    const float4* __restrict__ xr, const float4* __restrict__ xi,
    uint4* __restrict__ xc, int n4,
    const int* __restrict__ row, const int* __restrict__ col,
    const float* __restrict__ wsym, const float* __restrict__ qp,
    const float* __restrict__ ent, const float* __restrict__ cc,
    int* __restrict__ gcur, uint2* __restrict__ tmp,
    int E, int nbkt, int ntiles) {
  // feature pack (independent of binning; grid-stride)
  for (int i = blockIdx.x * 256 + threadIdx.x; i < n4; i += gridDim.x * 256) {
    float4 r = xr[i], m = xi[i];
    xc[i] = make_uint4(packh2(r.x, m.x), packh2(r.y, m.y),
                       packh2(r.z, m.z), packh2(r.w, m.w));
  }
  __shared__ int lcnt[NBKTMAX];
  __shared__ int lgp[NBKTMAX];
  __shared__ uint2 lbuf[NBKTMAX * CAP];
  const float q = qp[0];
  for (int t = blockIdx.x; t < ntiles; t += gridDim.x) {
    for (int i = threadIdx.x; i < nbkt; i += 256) lcnt[i] = 0;
    __syncthreads();
    int base = t * 2048;
#pragma unroll
    for (int j = 0; j < 8; ++j) {
      int e = base + j * 256 + threadIdx.x;
      if (e < E) {
        float ph = q * (ent[e] + cc[e]);
        float s = __sinf(ph), c = __cosf(ph);
        float w = wsym[e];
        int r = row[e];
        uint2 rec = make_uint2((unsigned)col[e] | ((unsigned)(r & 255) << 24),
                               packh2(w * c, w * s));
        int b = r >> 8;
        int pos = atomicAdd(&lcnt[b], 1);
        if (pos < CAP) lbuf[b * CAP + pos] = rec;
        else {  // rare overflow: direct store
          int gp = atomicAdd(&gcur[b], 1);
          tmp[gp] = rec;
        }
      }
    }
    __syncthreads();
    for (int b = threadIdx.x; b < nbkt; b += 256) {
      int c = lcnt[b];
      if (c > CAP) c = CAP;
      lgp[b] = (c > 0) ? atomicAdd(&gcur[b], c) : 0;
    }
    __syncthreads();
    int slots = nbkt * CAP;
    for (int i = threadIdx.x; i < slots; i += 256) {
      int b = i >> 4, j = i & (CAP - 1);
      int c = lcnt[b];
      if (c > CAP) c = CAP;
      if (j < c) tmp[lgp[b] + j] = lbuf[i];
    }
    __syncthreads();
  }
}

// ---- pass 2: per-chunk reorder + per-node offset computation --------------
__global__ void __launch_bounds__(256) fine_k(
    const uint2* __restrict__ tmp, const int* __restrict__ chbase,
    int* __restrict__ offs, uint2* __restrict__ crec, int N) {
  __shared__ int cntl[256];
  __shared__ int ls[256];
  __shared__ int fill[256];
  __shared__ int buf[256];
  int tid = threadIdx.x;
  int ch = blockIdx.x;
  int first = ch << 8;
  int beg = chbase[ch];
  int end = chbase[ch + 1];
  cntl[tid] = 0;
  fill[tid] = 0;
  __syncthreads();
  for (int i = beg + tid; i < end; i += 256)
    atomicAdd(&cntl[tmp[i].x >> 24], 1);
  __syncthreads();
  int v = cntl[tid];
  buf[tid] = v;
  __syncthreads();
  for (int d = 1; d < 256; d <<= 1) {
    int y = (tid >= d) ? buf[tid - d] : 0;
    __syncthreads();
    buf[tid] += y;
    __syncthreads();
  }
  int excl = buf[tid] - v;
  ls[tid] = excl;
  int n = first + tid;
  if (n < N) offs[n] = beg + excl;
  if (tid == 0 && ch == gridDim.x - 1) offs[N] = end;
  __syncthreads();
  for (int i = beg + tid; i < end; i += 256) {
    uint2 r = tmp[i];
    int loc = (int)(r.x >> 24);
    unsigned c = r.x & 0xFFFFFFu;
    int pos = beg + ls[loc] + atomicAdd(&fill[loc], 1);
    crec[pos] = make_uint2(c | ((unsigned)(loc & 15) << 28), r.y);
  }
}

// ---- streaming SPMM(16-node group) + MFMA GEMV ----------------------------
// A-frag (16x16x32 f16): lane holds A[lane&15][(lane>>4)*8+j]; A row = node.
// C/D: col(lane&15)=out-feature, row((lane>>4)*4+reg)=node.
struct AccRI {
  f32x4 r[4], i[4];
};

__device__ __forceinline__ AccRI spmm_gemv(
    const unsigned* __restrict__ tbl,
    const int* __restrict__ offs,
    const uint2* __restrict__ crec,
    const _Float16* __restrict__ sW,
    _Float16* __restrict__ s_ar, _Float16* __restrict__ s_ai,
    int n0, int N, int lane) {
  const int c16 = lane & 15, q16 = lane >> 4;
  int nend = n0 + 16;
  if (nend > N) nend = N;
  int ebeg = __builtin_amdgcn_readfirstlane(offs[n0]);
  int eend = __builtin_amdgcn_readfirstlane(offs[nend]);
  int total = eend - ebeg;

  uint2 rA[16], rB[16];
  unsigned vA[16], vB[16];
  float ar = 0.f, ai = 0.f;
  int ni = 0;

#define LOADRECS(base_, recs_)                                        \
  do {                                                                \
    if ((base_) + 16 <= total) {                                      \
      _Pragma("unroll") for (int j = 0; j < 16; ++j)                  \
          (recs_)[j] = crec[ebeg + (base_) + j];                      \
    } else {                                                          \
      _Pragma("unroll") for (int j = 0; j < 16; ++j) {                \
        int idx_ = ((base_) + j < total) ? ebeg + (base_) + j : ebeg; \
        (recs_)[j] = crec[idx_];                                      \
      }                                                               \
    }                                                                 \
  } while (0)

#define ISSUEV(recs_, v_)                                                  \
  do {                                                                     \
    _Pragma("unroll") for (int j = 0; j < 16; ++j)                         \
        (v_)[j] = tbl[(unsigned)((recs_)[j].x & 0x0FFFFFFFu) * 64u + lane]; \
  } while (0)

#define FLUSHTO(nrel_)                      \
  while (ni < (nrel_)) {                    \
    s_ar[ni * LW + lane] = (_Float16)ar;    \
    s_ai[ni * LW + lane] = (_Float16)ai;    \
    ar = 0.f;                               \
    ai = 0.f;                               \
    ++ni;                                   \
  }

#define CONSUME(recs_, v_, base_)                               \
  do {                                                          \
    _Pragma("unroll") for (int j = 0; j < 16; ++j) {            \
      if ((base_) + j >= total) break;                          \
      int nrel_ = (recs_)[j].x >> 28;                           \
      FLUSHTO(nrel_);                                           \
      float2 val_ = unpackh2((v_)[j]);                          \
      float2 wv_ = unpackh2((recs_)[j].y);                      \
      ar = fmaf(wv_.x, val_.x, fmaf(-wv_.y, val_.y, ar));       \
      ai = fmaf(wv_.y, val_.x, fmaf(wv_.x, val_.y, ai));        \
    }                                                           \
  } while (0)

  int nbatch = (total + 15) >> 4;
  if (nbatch > 0) {
    LOADRECS(0, rA);
    ISSUEV(rA, vA);
    if (nbatch > 1) LOADRECS(16, rB);
    for (int b = 0; b < nbatch; b += 2) {
      if (b + 1 < nbatch) ISSUEV(rB, vB);
      CONSUME(rA, vA, b * 16);
      if (b + 2 < nbatch) LOADRECS((b + 2) * 16, rA);
      if (b + 1 < nbatch) {
        if (b + 2 < nbatch) ISSUEV(rA, vA);
        CONSUME(rB, vB, (b + 1) * 16);
        if (b + 3 < nbatch) LOADRECS((b + 3) * 16, rB);
      }
    }
  }
  FLUSHTO(16);
#undef LOADRECS
#undef ISSUEV
#undef FLUSHTO
#undef CONSUME

  half8 a_r[2], a_i[2];
#pragma unroll
  for (int ks = 0; ks < 2; ++ks) {
    int off = c16 * LW + ks * 32 + q16 * 8;
    a_r[ks] = *(const half8*)&s_ar[off];
    a_i[ks] = *(const half8*)&s_ai[off];
  }
  AccRI acc;
#pragma unroll
  for (int nt = 0; nt < 4; ++nt) {
    acc.r[nt] = (f32x4){0.f, 0.f, 0.f, 0.f};
    acc.i[nt] = (f32x4){0.f, 0.f, 0.f, 0.f};
  }
#pragma unroll
  for (int nt = 0; nt < 4; ++nt)
#pragma unroll
    for (int ks = 0; ks < 2; ++ks) {
      half8 b = *(const half8*)&sW[(nt * 16 + c16) * LW + ks * 32 + q16 * 8];
      acc.r[nt] = __builtin_amdgcn_mfma_f32_16x16x32_f16(a_r[ks], b, acc.r[nt], 0, 0, 0);
      acc.i[nt] = __builtin_amdgcn_mfma_f32_16x16x32_f16(a_i[ks], b, acc.i[nt], 0, 0, 0);
    }
  return acc;
}

// ---- layer 1 (8 waves/block, static group map, weight LDS) ----------------
__global__ void __launch_bounds__(512, 6) layer1_k(
    const unsigned* __restrict__ xc,
    const int* __restrict__ offs,
    const uint2* __restrict__ crec,
    const float* __restrict__ W, const float* __restrict__ bias,
    unsigned* __restrict__ Hc, int N) {
  __shared__ __align__(16) _Float16 sW[64 * LW];
  __shared__ __align__(16) _Float16 s_act[8][2][16 * LW];
  for (int i = threadIdx.x; i < 64 * 64; i += 512)
    sW[(i >> 6) * LW + (i & 63)] = (_Float16)W[i];
  __syncthreads();
  const int w = threadIdx.x >> 6, lane = threadIdx.x & 63;
  const int c16 = lane & 15, q16 = lane >> 4;
  int n0 = (blockIdx.x * 8 + w) * 16;
  if (n0 >= N) return;
  float bl[4];
#pragma unroll
  for (int nt = 0; nt < 4; ++nt) bl[nt] = 2.f * bias[nt * 16 + c16];

  AccRI acc = spmm_gemv(xc, offs, crec, sW,
                        &s_act[w][0][0], &s_act[w][1][0], n0, N, lane);
#pragma unroll
  for (int nt = 0; nt < 4; ++nt)
#pragma unroll
    for (int r = 0; r < 4; ++r) {
      int node = n0 + q16 * 4 + r;
      if (node < N) {
        float hr = fmaxf(acc.r[nt][r], 0.f);
        float hi = fmaxf(acc.i[nt][r] + bl[nt], 0.f);
        Hc[(unsigned)node * 64u + nt * 16 + c16] = packh2(hr, hi);
      }
    }
}

// ---- layer 2 + final [16x128] projection (8 waves/block) ------------------
__global__ void __launch_bounds__(512, 6) layer2_k(
    const unsigned* __restrict__ Hc,
    const int* __restrict__ offs,
    const uint2* __restrict__ crec,
    const float* __restrict__ W2, const float* __restrict__ b2,
    const float* __restrict__ W3, const float* __restrict__ b3,
    float* __restrict__ out, int N) {
  __shared__ __align__(16) _Float16 sW[64 * LW];
  __shared__ __align__(16) _Float16 sW3p[16 * LW3];
  __shared__ __align__(16) _Float16 s_act[8][2][16 * LW];
  for (int i = threadIdx.x; i < 64 * 64; i += 512)
    sW[(i >> 6) * LW + (i & 63)] = (_Float16)W2[i];
  // interleaved k' = 2f + (0:real,1:imag)  ->  source W3[o][f + 64*ri]
  for (int i = threadIdx.x; i < 16 * 128; i += 512) {
    int o = i >> 7, kp = i & 127;
    sW3p[o * LW3 + kp] = (_Float16)W3[o * 128 + (kp >> 1) + 64 * (kp & 1)];
  }
  __syncthreads();
  const int w = threadIdx.x >> 6, lane = threadIdx.x & 63;
  const int c16 = lane & 15, q16 = lane >> 4;
  int n0 = (blockIdx.x * 8 + w) * 16;
  if (n0 >= N) return;
  float bl[4];
#pragma unroll
  for (int nt = 0; nt < 4; ++nt) bl[nt] = 2.f * b2[nt * 16 + c16];
  const float b3v = b3[c16];

  AccRI acc = spmm_gemv(Hc, offs, crec, sW,
                        &s_act[w][0][0], &s_act[w][1][0], n0, N, lane);

  // stage h packed (r,i) per feature into proj buffer (reuses act LDS)
  unsigned* pb = (unsigned*)&s_act[w][0][0];  // [16][68] u32 rows = 136 halves
#pragma unroll
  for (int nt = 0; nt < 4; ++nt)
#pragma unroll
    for (int r = 0; r < 4; ++r) {
      float hr = fmaxf(acc.r[nt][r], 0.f);
      float hi = fmaxf(acc.i[nt][r] + bl[nt], 0.f);
      pb[(q16 * 4 + r) * 68 + nt * 16 + c16] = packh2(hr, hi);
    }
  f32x4 po = {0.f, 0.f, 0.f, 0.f};
#pragma unroll
  for (int ks = 0; ks < 4; ++ks) {
    half8 a = *(const half8*)((const _Float16*)pb + c16 * LW3 + ks * 32 + q16 * 8);
    half8 b = *(const half8*)&sW3p[c16 * LW3 + ks * 32 + q16 * 8];
    po = __builtin_amdgcn_mfma_f32_16x16x32_f16(a, b, po, 0, 0, 0);
  }
#pragma unroll
  for (int r = 0; r < 4; ++r) {
    int node = n0 + q16 * 4 + r;
    if (node < N) out[(unsigned)node * 16u + c16] = po[r] + b3v;
  }
}

extern "C" void kernel_launch(void* const* d_in, const int* in_sizes, int n_in,
                              void* d_out, int out_size, void* d_ws, size_t ws_size,
                              hipStream_t stream) {
  const float* xr   = (const float*)d_in[0];
  const float* xi   = (const float*)d_in[1];
  const float* wsym = (const float*)d_in[2];
  const float* qp   = (const float*)d_in[3];
  const float* ent  = (const float*)d_in[4];
  const float* cc   = (const float*)d_in[5];
  const float* W1   = (const float*)d_in[6];
  const float* b1   = (const float*)d_in[7];
  const float* W2   = (const float*)d_in[8];
  const float* b2   = (const float*)d_in[9];
  const float* W3   = (const float*)d_in[10];
  const float* b3   = (const float*)d_in[11];
  const int*   row  = (const int*)d_in[12];
  const int*   col  = (const int*)d_in[13];
  const int N = in_sizes[0] / 64;
  const int E = in_sizes[2];
  float* out = (float*)d_out;

  char* ws = (char*)d_ws;
  size_t off = 0;
  auto alloc = [&](size_t bytes) -> void* {
    void* p = ws + off;
    off += (bytes + 255) & ~(size_t)255;
    return p;
  };
  int*      hist_part = (int*)alloc((size_t)HBLK * NBKTMAX * 4);
  int*      chbase    = (int*)alloc((size_t)(NBKTMAX + 1) * 4);
  int*      gcur      = (int*)alloc((size_t)NBKTMAX * 4);
  int*      offs      = (int*)alloc((size_t)(N + 1) * 4);
  uint2*    crec      = (uint2*)alloc((size_t)E * 8);
  unsigned* xc        = (unsigned*)alloc((size_t)N * 64 * 4);
  unsigned* Hc        = (unsigned*)alloc((size_t)N * 64 * 4);
  uint2*    tmp       = (uint2*)Hc;  // alias: tmp dead before layer1 writes Hc

  int nch = (N + 255) / 256;  // == nbkt (<= NBKTMAX)
  int ntiles = (E + 2047) / 2048;
  hist_k<<<HBLK, 256, 0, stream>>>(row, hist_part, E, nch);
  cscan_k<<<1, 512, 0, stream>>>(hist_part, chbase, gcur, nch, E);
  int n4 = N * 64 / 4;
  bin_k<<<ntiles, 256, 0, stream>>>((const float4*)xr, (const float4*)xi,
                                    (uint4*)xc, n4, row, col, wsym, qp, ent, cc,
                                    gcur, tmp, E, nch, ntiles);
  fine_k<<<nch, 256, 0, stream>>>(tmp, chbase, offs, crec, N);
  int nb = (N + 127) / 128;  // 8 waves/block x 16 nodes/wave, static map
  layer1_k<<<nb, 512, 0, stream>>>(xc, offs, crec, W1, b1, Hc, N);
  layer2_k<<<nb, 512, 0, stream>>>(Hc, offs, crec, W2, b2, W3, b3, out, N);
}